// Round 1
// baseline (835.665 us; speedup 1.0000x reference)
//
#include <hip/hip_runtime.h>
#include <hip/hip_bf16.h>

// ---------------------------------------------------------------------------
// GCN: out = relu(Agg(x@W1)+b1) -> relu(Agg(.@W2)+b2) -> .@Wc+bc
// Agg(h)[i] = dinv[i]^2*h[i] + sum_{e: dst=i} dinv[i]*dinv[src]*h[src]
// deg = in-degree(dst) + 1, dinv = rsqrt(deg)
// CSR built on-device each launch (harness restores inputs / poisons ws).
// ---------------------------------------------------------------------------

// ------------------------- preprocessing kernels ---------------------------

__global__ __launch_bounds__(256) void k_deg(const int* __restrict__ dst,
                                             int* __restrict__ deg, int E) {
    int i = blockIdx.x * 256 + threadIdx.x;
    if (i < E) atomicAdd(&deg[dst[i]], 1);
}

__global__ __launch_bounds__(256) void k_dinv(const int* __restrict__ deg,
                                              float* __restrict__ dinv, int n) {
    int i = blockIdx.x * 256 + threadIdx.x;
    if (i < n) dinv[i] = rsqrtf((float)(deg[i] + 1));
}

__device__ inline int block_incl_scan_256(int t, int* tmp) {
    int tid = threadIdx.x;
    tmp[tid] = t;
    __syncthreads();
    #pragma unroll
    for (int off = 1; off < 256; off <<= 1) {
        int v = (tid >= off) ? tmp[tid - off] : 0;
        __syncthreads();
        tmp[tid] += v;
        __syncthreads();
    }
    return tmp[tid];
}

// chunk of 1024 elems per block (256 thr x 4)
__global__ __launch_bounds__(256) void k_scan1(const int* __restrict__ deg,
                                               int* __restrict__ bsum, int n) {
    __shared__ int tmp[256];
    int base = blockIdx.x * 1024;
    int t = 0;
    #pragma unroll
    for (int l = 0; l < 4; ++l) {
        int i = base + threadIdx.x * 4 + l;
        t += (i < n) ? deg[i] : 0;
    }
    block_incl_scan_256(t, tmp);
    if (threadIdx.x == 0) bsum[blockIdx.x] = tmp[255];
}

__global__ __launch_bounds__(256) void k_scan2(int* __restrict__ bsum, int nb) {
    __shared__ int tmp[256];
    int tid = threadIdx.x;
    int v = (tid < nb) ? bsum[tid] : 0;
    block_incl_scan_256(v, tmp);
    if (tid < nb) bsum[tid] = tid ? tmp[tid - 1] : 0;
}

__global__ __launch_bounds__(256) void k_scan3(const int* __restrict__ deg,
                                               const int* __restrict__ bsum,
                                               int* __restrict__ rowptr, int n) {
    __shared__ int tmp[256];
    int base = blockIdx.x * 1024;
    int v[4];
    int t = 0;
    #pragma unroll
    for (int l = 0; l < 4; ++l) {
        int i = base + threadIdx.x * 4 + l;
        v[l] = (i < n) ? deg[i] : 0;
        t += v[l];
    }
    block_incl_scan_256(t, tmp);
    int run = bsum[blockIdx.x] + (threadIdx.x ? tmp[threadIdx.x - 1] : 0);
    #pragma unroll
    for (int l = 0; l < 4; ++l) {
        int i = base + threadIdx.x * 4 + l;
        if (i < n) rowptr[i] = run;
        run += v[l];
    }
}

__global__ __launch_bounds__(256) void k_cursor(int* __restrict__ rowptr,
                                                int* __restrict__ cursor,
                                                int n, int E) {
    int i = blockIdx.x * 256 + threadIdx.x;
    if (i < n) cursor[i] = rowptr[i];
    if (i == 0) rowptr[n] = E;
}

__global__ __launch_bounds__(256) void k_scatter(const int* __restrict__ src,
                                                 const int* __restrict__ dst,
                                                 int* __restrict__ cursor,
                                                 int* __restrict__ colArr, int E) {
    int i = blockIdx.x * 256 + threadIdx.x;
    if (i < E) {
        int d = dst[i];
        int p = atomicAdd(&cursor[d], 1);
        colArr[p] = src[i];
    }
}

// ------------------------------- GEMM --------------------------------------
// C[M,N] = A[M,K] @ W[K,N] (+bias). BM=64, BK=32, BN = 64*NCOL4.
// 256 threads: thread handles 4 rows x (4*NCOL4) cols.

template <int K, int NCOL4>
__global__ __launch_bounds__(256) void gemm_xw(const float* __restrict__ A,
                                               const float* __restrict__ W,
                                               const float* __restrict__ bias,
                                               float* __restrict__ C,
                                               int M, int N) {
    constexpr int BK = 32;
    constexpr int BN = 64 * NCOL4;
    __shared__ __align__(16) float xs[BK][68];   // transposed [k][row], stride 68 keeps b128 16B-aligned
    __shared__ __align__(16) float ws[BK][BN];   // [k][col]

    const int tid = threadIdx.x;
    const int bm  = blockIdx.x * 64;
    const int cg  = tid & 15;
    const int rg  = tid >> 4;    // 0..15
    const int r0  = rg * 4;
    const int c0  = cg * 4;

    float acc[4][NCOL4 * 4];
    #pragma unroll
    for (int r = 0; r < 4; ++r)
        #pragma unroll
        for (int j = 0; j < NCOL4 * 4; ++j) acc[r][j] = 0.f;

    for (int k0 = 0; k0 < K; k0 += BK) {
        // x tile: 64 rows x 32 k = 512 float4; 2 per thread
        #pragma unroll
        for (int l = 0; l < 2; ++l) {
            int f4  = tid + l * 256;
            int row = f4 >> 3;
            int kk  = (f4 & 7) << 2;
            float4 v = make_float4(0.f, 0.f, 0.f, 0.f);
            int grow = bm + row;
            if (grow < M)
                v = *(const float4*)(A + (size_t)grow * K + k0 + kk);
            xs[kk + 0][row] = v.x;
            xs[kk + 1][row] = v.y;
            xs[kk + 2][row] = v.z;
            xs[kk + 3][row] = v.w;
        }
        // W tile
        if (NCOL4 == 2) {  // N == 128 exactly
            #pragma unroll
            for (int l = 0; l < 4; ++l) {
                int idx = tid + l * 256;     // 0..1023
                int kk  = idx >> 5;
                int cc  = (idx & 31) << 2;
                *(float4*)&ws[kk][cc] =
                    *(const float4*)(W + (size_t)(k0 + kk) * N + cc);
            }
        } else {           // padded BN=64, N may be < 64 (classifier N=40)
            #pragma unroll
            for (int l = 0; l < 8; ++l) {
                int idx = tid + l * 256;     // 0..2047
                int kk  = idx >> 6;
                int cc  = idx & 63;
                ws[kk][cc] = (cc < N) ? W[(size_t)(k0 + kk) * N + cc] : 0.f;
            }
        }
        __syncthreads();

        #pragma unroll
        for (int kk = 0; kk < BK; ++kk) {
            float4 xv = *(const float4*)&xs[kk][r0];
            float4 w0 = *(const float4*)&ws[kk][c0];
            float4 w1 = (NCOL4 == 2) ? *(const float4*)&ws[kk][c0 + 64]
                                     : make_float4(0.f, 0.f, 0.f, 0.f);
            float xr[4] = {xv.x, xv.y, xv.z, xv.w};
            #pragma unroll
            for (int r = 0; r < 4; ++r) {
                acc[r][0] += xr[r] * w0.x;
                acc[r][1] += xr[r] * w0.y;
                acc[r][2] += xr[r] * w0.z;
                acc[r][3] += xr[r] * w0.w;
                if (NCOL4 == 2) {
                    acc[r][4] += xr[r] * w1.x;
                    acc[r][5] += xr[r] * w1.y;
                    acc[r][6] += xr[r] * w1.z;
                    acc[r][7] += xr[r] * w1.w;
                }
            }
        }
        __syncthreads();
    }

    #pragma unroll
    for (int r = 0; r < 4; ++r) {
        int grow = bm + r0 + r;
        if (grow >= M) continue;
        #pragma unroll
        for (int g = 0; g < NCOL4; ++g) {
            int cc = c0 + g * 64;
            if (cc >= N) continue;   // classifier: N=40, multiple of 4
            float4 o;
            o.x = acc[r][g * 4 + 0];
            o.y = acc[r][g * 4 + 1];
            o.z = acc[r][g * 4 + 2];
            o.w = acc[r][g * 4 + 3];
            if (bias) {
                o.x += bias[cc + 0];
                o.y += bias[cc + 1];
                o.z += bias[cc + 2];
                o.w += bias[cc + 3];
            }
            *(float4*)(C + (size_t)grow * N + cc) = o;
        }
    }
}

// ---------------------------- aggregation ----------------------------------
// One wave per node; lane covers 2 cols (float2) of the 128-wide row.
// out[i] = act( dinv[i]^2*h[i] + sum_e dinv[i]*dinv[col[e]]*h[col[e]] + b )

__global__ __launch_bounds__(256) void gcn_agg(const float* __restrict__ h,
                                               const int* __restrict__ rowptr,
                                               const int* __restrict__ colArr,
                                               const float* __restrict__ dinv,
                                               const float* __restrict__ bias,
                                               float* __restrict__ out,
                                               int n, int do_relu) {
    int node = blockIdx.x * 4 + (threadIdx.x >> 6);
    if (node >= n) return;
    int lane = threadIdx.x & 63;

    float di = dinv[node];
    float2 v = ((const float2*)(h + (size_t)node * 128))[lane];
    float s  = di * di;
    float accx = v.x * s;
    float accy = v.y * s;

    int e0 = rowptr[node];
    int e1 = rowptr[node + 1];
    int j  = (e0 < e1) ? colArr[e0] : 0;
    for (int e = e0; e < e1; ++e) {
        int jn = (e + 1 < e1) ? colArr[e + 1] : 0;   // prefetch next index
        float w  = di * dinv[j];
        float2 u = ((const float2*)(h + (size_t)j * 128))[lane];
        accx += u.x * w;
        accy += u.y * w;
        j = jn;
    }

    float2 b = ((const float2*)bias)[lane];
    float ox = accx + b.x;
    float oy = accy + b.y;
    if (do_relu) {
        ox = fmaxf(ox, 0.f);
        oy = fmaxf(oy, 0.f);
    }
    ((float2*)(out + (size_t)node * 128))[lane] = make_float2(ox, oy);
}

// ------------------------------- launch ------------------------------------

extern "C" void kernel_launch(void* const* d_in, const int* in_sizes, int n_in,
                              void* d_out, int out_size, void* d_ws, size_t ws_size,
                              hipStream_t stream) {
    const float* x  = (const float*)d_in[0];
    const int* eidx = (const int*)d_in[1];
    const float* W1 = (const float*)d_in[2];
    const float* b1 = (const float*)d_in[3];
    const float* W2 = (const float*)d_in[4];
    const float* b2 = (const float*)d_in[5];
    const float* Wc = (const float*)d_in[6];
    const float* bc = (const float*)d_in[7];
    float* out = (float*)d_out;

    const int NF = 256, NH = 128, NC = 40;
    const int n = in_sizes[0] / NF;    // 100000
    const int E = in_sizes[1] / 2;     // 1600000
    const int* src = eidx;
    const int* dst = eidx + E;

    char* wsb = (char*)d_ws;
    size_t off = 0;
    auto alloc = [&](size_t bytes) {
        char* p = wsb + off;
        off = (off + bytes + 511) & ~(size_t)511;
        return p;
    };
    float* bufA  = (float*)alloc((size_t)n * NH * 4);   // 51.2 MB
    float* bufB  = (float*)alloc((size_t)n * NH * 4);   // 51.2 MB
    int* deg     = (int*)alloc((size_t)n * 4);
    int* rowptr  = (int*)alloc((size_t)(n + 1) * 4);
    int* cursor  = (int*)alloc((size_t)n * 4);
    int* colArr  = (int*)alloc((size_t)E * 4);          // 6.4 MB
    float* dinv  = (float*)alloc((size_t)n * 4);
    int* bsum    = (int*)alloc(1024);

    const int gE = (E + 255) / 256;
    const int gN = (n + 255) / 256;
    const int nb = (n + 1023) / 1024;  // 98 <= 256

    hipMemsetAsync(deg, 0, (size_t)n * 4, stream);
    k_deg<<<gE, 256, 0, stream>>>(dst, deg, E);
    k_dinv<<<gN, 256, 0, stream>>>(deg, dinv, n);
    k_scan1<<<nb, 256, 0, stream>>>(deg, bsum, n);
    k_scan2<<<1, 256, 0, stream>>>(bsum, nb);
    k_scan3<<<nb, 256, 0, stream>>>(deg, bsum, rowptr, n);
    k_cursor<<<gN, 256, 0, stream>>>(rowptr, cursor, n, E);
    k_scatter<<<gE, 256, 0, stream>>>(src, dst, cursor, colArr, E);

    const int gM = (n + 63) / 64;     // 1563
    gemm_xw<256, 2><<<gM, 256, 0, stream>>>(x, W1, nullptr, bufA, n, NH);
    gcn_agg<<<(n + 3) / 4, 256, 0, stream>>>(bufA, rowptr, colArr, dinv, b1, bufB, n, 1);
    gemm_xw<128, 2><<<gM, 256, 0, stream>>>(bufB, W2, nullptr, bufA, n, NH);
    gcn_agg<<<(n + 3) / 4, 256, 0, stream>>>(bufA, rowptr, colArr, dinv, b2, bufB, n, 1);
    gemm_xw<128, 1><<<gM, 256, 0, stream>>>(bufB, Wc, bc, out, n, NC);
}

// Round 2
// 728.654 us; speedup vs baseline: 1.1469x; 1.1469x over previous
//
#include <hip/hip_runtime.h>
#include <hip/hip_bf16.h>

// ---------------------------------------------------------------------------
// GCN: out = relu(Agg(x@W1)+b1) -> relu(Agg(.@W2)+b2) -> .@Wc+bc
// Agg(h)[i] = dinv[i]^2*h[i] + sum_{e: dst=i} dinv[i]*dinv[src]*h[src]
// deg = in-degree(dst) + 1, dinv = rsqrt(deg)
// CSR built on-device each launch (harness restores inputs / poisons ws).
// R1: agg edge-loop unrolled x4 for MLP (was latency-bound, VALUBusy 20%,
//     hbm 33%, VGPR=12 -> single gather in flight per wave).
// ---------------------------------------------------------------------------

// ------------------------- preprocessing kernels ---------------------------

__global__ __launch_bounds__(256) void k_deg(const int* __restrict__ dst,
                                             int* __restrict__ deg, int E) {
    int i = blockIdx.x * 256 + threadIdx.x;
    if (i < E) atomicAdd(&deg[dst[i]], 1);
}

__device__ inline int block_incl_scan_256(int t, int* tmp) {
    int tid = threadIdx.x;
    tmp[tid] = t;
    __syncthreads();
    #pragma unroll
    for (int off = 1; off < 256; off <<= 1) {
        int v = (tid >= off) ? tmp[tid - off] : 0;
        __syncthreads();
        tmp[tid] += v;
        __syncthreads();
    }
    return tmp[tid];
}

// chunk of 1024 elems per block (256 thr x 4)
__global__ __launch_bounds__(256) void k_scan1(const int* __restrict__ deg,
                                               int* __restrict__ bsum, int n) {
    __shared__ int tmp[256];
    int base = blockIdx.x * 1024;
    int t = 0;
    #pragma unroll
    for (int l = 0; l < 4; ++l) {
        int i = base + threadIdx.x * 4 + l;
        t += (i < n) ? deg[i] : 0;
    }
    block_incl_scan_256(t, tmp);
    if (threadIdx.x == 0) bsum[blockIdx.x] = tmp[255];
}

__global__ __launch_bounds__(256) void k_scan2(int* __restrict__ bsum, int nb) {
    __shared__ int tmp[256];
    int tid = threadIdx.x;
    int v = (tid < nb) ? bsum[tid] : 0;
    block_incl_scan_256(v, tmp);
    if (tid < nb) bsum[tid] = tid ? tmp[tid - 1] : 0;
}

__global__ __launch_bounds__(256) void k_scan3(const int* __restrict__ deg,
                                               const int* __restrict__ bsum,
                                               int* __restrict__ rowptr, int n) {
    __shared__ int tmp[256];
    int base = blockIdx.x * 1024;
    int v[4];
    int t = 0;
    #pragma unroll
    for (int l = 0; l < 4; ++l) {
        int i = base + threadIdx.x * 4 + l;
        v[l] = (i < n) ? deg[i] : 0;
        t += v[l];
    }
    block_incl_scan_256(t, tmp);
    int run = bsum[blockIdx.x] + (threadIdx.x ? tmp[threadIdx.x - 1] : 0);
    #pragma unroll
    for (int l = 0; l < 4; ++l) {
        int i = base + threadIdx.x * 4 + l;
        if (i < n) rowptr[i] = run;
        run += v[l];
    }
}

// cursor init + dinv + rowptr[n]=E (fused elementwise pass)
__global__ __launch_bounds__(256) void k_cursor_dinv(int* __restrict__ rowptr,
                                                     int* __restrict__ cursor,
                                                     const int* __restrict__ deg,
                                                     float* __restrict__ dinv,
                                                     int n, int E) {
    int i = blockIdx.x * 256 + threadIdx.x;
    if (i < n) {
        cursor[i] = rowptr[i];
        dinv[i] = rsqrtf((float)(deg[i] + 1));
    }
    if (i == 0) rowptr[n] = E;
}

__global__ __launch_bounds__(256) void k_scatter(const int* __restrict__ src,
                                                 const int* __restrict__ dst,
                                                 int* __restrict__ cursor,
                                                 int* __restrict__ colArr, int E) {
    int i = blockIdx.x * 256 + threadIdx.x;
    if (i < E) {
        int d = dst[i];
        int p = atomicAdd(&cursor[d], 1);
        colArr[p] = src[i];
    }
}

// ------------------------------- GEMM --------------------------------------
// C[M,N] = A[M,K] @ W[K,N] (+bias). BM=64, BK=32, BN = 64*NCOL4.
// 256 threads: thread handles 4 rows x (4*NCOL4) cols.

template <int K, int NCOL4>
__global__ __launch_bounds__(256) void gemm_xw(const float* __restrict__ A,
                                               const float* __restrict__ W,
                                               const float* __restrict__ bias,
                                               float* __restrict__ C,
                                               int M, int N) {
    constexpr int BK = 32;
    constexpr int BN = 64 * NCOL4;
    __shared__ __align__(16) float xs[BK][68];   // transposed [k][row], stride 68 keeps b128 16B-aligned
    __shared__ __align__(16) float ws[BK][BN];   // [k][col]

    const int tid = threadIdx.x;
    const int bm  = blockIdx.x * 64;
    const int cg  = tid & 15;
    const int rg  = tid >> 4;    // 0..15
    const int r0  = rg * 4;
    const int c0  = cg * 4;

    float acc[4][NCOL4 * 4];
    #pragma unroll
    for (int r = 0; r < 4; ++r)
        #pragma unroll
        for (int j = 0; j < NCOL4 * 4; ++j) acc[r][j] = 0.f;

    for (int k0 = 0; k0 < K; k0 += BK) {
        // x tile: 64 rows x 32 k = 512 float4; 2 per thread
        #pragma unroll
        for (int l = 0; l < 2; ++l) {
            int f4  = tid + l * 256;
            int row = f4 >> 3;
            int kk  = (f4 & 7) << 2;
            float4 v = make_float4(0.f, 0.f, 0.f, 0.f);
            int grow = bm + row;
            if (grow < M)
                v = *(const float4*)(A + (size_t)grow * K + k0 + kk);
            xs[kk + 0][row] = v.x;
            xs[kk + 1][row] = v.y;
            xs[kk + 2][row] = v.z;
            xs[kk + 3][row] = v.w;
        }
        // W tile
        if (NCOL4 == 2) {  // N == 128 exactly
            #pragma unroll
            for (int l = 0; l < 4; ++l) {
                int idx = tid + l * 256;     // 0..1023
                int kk  = idx >> 5;
                int cc  = (idx & 31) << 2;
                *(float4*)&ws[kk][cc] =
                    *(const float4*)(W + (size_t)(k0 + kk) * N + cc);
            }
        } else {           // padded BN=64, N may be < 64 (classifier N=40)
            #pragma unroll
            for (int l = 0; l < 8; ++l) {
                int idx = tid + l * 256;     // 0..2047
                int kk  = idx >> 6;
                int cc  = idx & 63;
                ws[kk][cc] = (cc < N) ? W[(size_t)(k0 + kk) * N + cc] : 0.f;
            }
        }
        __syncthreads();

        #pragma unroll
        for (int kk = 0; kk < BK; ++kk) {
            float4 xv = *(const float4*)&xs[kk][r0];
            float4 w0 = *(const float4*)&ws[kk][c0];
            float4 w1 = (NCOL4 == 2) ? *(const float4*)&ws[kk][c0 + 64]
                                     : make_float4(0.f, 0.f, 0.f, 0.f);
            float xr[4] = {xv.x, xv.y, xv.z, xv.w};
            #pragma unroll
            for (int r = 0; r < 4; ++r) {
                acc[r][0] += xr[r] * w0.x;
                acc[r][1] += xr[r] * w0.y;
                acc[r][2] += xr[r] * w0.z;
                acc[r][3] += xr[r] * w0.w;
                if (NCOL4 == 2) {
                    acc[r][4] += xr[r] * w1.x;
                    acc[r][5] += xr[r] * w1.y;
                    acc[r][6] += xr[r] * w1.z;
                    acc[r][7] += xr[r] * w1.w;
                }
            }
        }
        __syncthreads();
    }

    #pragma unroll
    for (int r = 0; r < 4; ++r) {
        int grow = bm + r0 + r;
        if (grow >= M) continue;
        #pragma unroll
        for (int g = 0; g < NCOL4; ++g) {
            int cc = c0 + g * 64;
            if (cc >= N) continue;   // classifier: N=40, multiple of 4
            float4 o;
            o.x = acc[r][g * 4 + 0];
            o.y = acc[r][g * 4 + 1];
            o.z = acc[r][g * 4 + 2];
            o.w = acc[r][g * 4 + 3];
            if (bias) {
                o.x += bias[cc + 0];
                o.y += bias[cc + 1];
                o.z += bias[cc + 2];
                o.w += bias[cc + 3];
            }
            *(float4*)(C + (size_t)grow * N + cc) = o;
        }
    }
}

// ---------------------------- aggregation ----------------------------------
// One wave per node; lane covers 2 cols (float2) of the 128-wide row.
// Edge loop unrolled x4: 4 independent row-gathers in flight per wave (MLP),
// breaking the colArr->gather->fma serial chain that left VGPR=12 / 1 load
// outstanding in R0.

__global__ __launch_bounds__(256) void gcn_agg(const float* __restrict__ h,
                                               const int* __restrict__ rowptr,
                                               const int* __restrict__ colArr,
                                               const float* __restrict__ dinv,
                                               const float* __restrict__ bias,
                                               float* __restrict__ out,
                                               int n, int do_relu) {
    int node = blockIdx.x * 4 + (threadIdx.x >> 6);
    if (node >= n) return;
    int lane = threadIdx.x & 63;
    const float2* __restrict__ hp = (const float2*)h;

    float di = dinv[node];
    float2 v = hp[(size_t)node * 64 + lane];
    float s  = di * di;
    float accx = v.x * s;
    float accy = v.y * s;

    int e0 = rowptr[node];
    int e1 = rowptr[node + 1];
    int e  = e0;

    for (; e + 4 <= e1; e += 4) {
        int j0 = colArr[e + 0];
        int j1 = colArr[e + 1];
        int j2 = colArr[e + 2];
        int j3 = colArr[e + 3];
        float w0 = dinv[j0];
        float w1 = dinv[j1];
        float w2 = dinv[j2];
        float w3 = dinv[j3];
        float2 u0 = hp[(size_t)j0 * 64 + lane];
        float2 u1 = hp[(size_t)j1 * 64 + lane];
        float2 u2 = hp[(size_t)j2 * 64 + lane];
        float2 u3 = hp[(size_t)j3 * 64 + lane];
        w0 *= di; w1 *= di; w2 *= di; w3 *= di;
        accx += u0.x * w0;
        accy += u0.y * w0;
        accx += u1.x * w1;
        accy += u1.y * w1;
        accx += u2.x * w2;
        accy += u2.y * w2;
        accx += u3.x * w3;
        accy += u3.y * w3;
    }
    for (; e < e1; ++e) {
        int j = colArr[e];
        float w = di * dinv[j];
        float2 u = hp[(size_t)j * 64 + lane];
        accx += u.x * w;
        accy += u.y * w;
    }

    float2 b = ((const float2*)bias)[lane];
    float ox = accx + b.x;
    float oy = accy + b.y;
    if (do_relu) {
        ox = fmaxf(ox, 0.f);
        oy = fmaxf(oy, 0.f);
    }
    ((float2*)(out + (size_t)node * 128))[lane] = make_float2(ox, oy);
}

// ------------------------------- launch ------------------------------------

extern "C" void kernel_launch(void* const* d_in, const int* in_sizes, int n_in,
                              void* d_out, int out_size, void* d_ws, size_t ws_size,
                              hipStream_t stream) {
    const float* x  = (const float*)d_in[0];
    const int* eidx = (const int*)d_in[1];
    const float* W1 = (const float*)d_in[2];
    const float* b1 = (const float*)d_in[3];
    const float* W2 = (const float*)d_in[4];
    const float* b2 = (const float*)d_in[5];
    const float* Wc = (const float*)d_in[6];
    const float* bc = (const float*)d_in[7];
    float* out = (float*)d_out;

    const int NF = 256, NH = 128, NC = 40;
    const int n = in_sizes[0] / NF;    // 100000
    const int E = in_sizes[1] / 2;     // 1600000
    const int* src = eidx;
    const int* dst = eidx + E;

    char* wsb = (char*)d_ws;
    size_t off = 0;
    auto alloc = [&](size_t bytes) {
        char* p = wsb + off;
        off = (off + bytes + 511) & ~(size_t)511;
        return p;
    };
    float* bufA  = (float*)alloc((size_t)n * NH * 4);   // 51.2 MB
    float* bufB  = (float*)alloc((size_t)n * NH * 4);   // 51.2 MB
    int* deg     = (int*)alloc((size_t)n * 4);
    int* rowptr  = (int*)alloc((size_t)(n + 1) * 4);
    int* cursor  = (int*)alloc((size_t)n * 4);
    int* colArr  = (int*)alloc((size_t)E * 4);          // 6.4 MB
    float* dinv  = (float*)alloc((size_t)n * 4);
    int* bsum    = (int*)alloc(1024);

    const int gE = (E + 255) / 256;
    const int gN = (n + 255) / 256;
    const int nb = (n + 1023) / 1024;  // 98 <= 256

    hipMemsetAsync(deg, 0, (size_t)n * 4, stream);
    k_deg<<<gE, 256, 0, stream>>>(dst, deg, E);
    k_scan1<<<nb, 256, 0, stream>>>(deg, bsum, n);
    k_scan2<<<1, 256, 0, stream>>>(bsum, nb);
    k_scan3<<<nb, 256, 0, stream>>>(deg, bsum, rowptr, n);
    k_cursor_dinv<<<gN, 256, 0, stream>>>(rowptr, cursor, deg, dinv, n, E);
    k_scatter<<<gE, 256, 0, stream>>>(src, dst, cursor, colArr, E);

    const int gM = (n + 63) / 64;     // 1563
    gemm_xw<256, 2><<<gM, 256, 0, stream>>>(x, W1, nullptr, bufA, n, NH);
    gcn_agg<<<(n + 3) / 4, 256, 0, stream>>>(bufA, rowptr, colArr, dinv, b1, bufB, n, 1);
    gemm_xw<128, 2><<<gM, 256, 0, stream>>>(bufB, W2, nullptr, bufA, n, NH);
    gcn_agg<<<(n + 3) / 4, 256, 0, stream>>>(bufA, rowptr, colArr, dinv, b2, bufB, n, 1);
    gemm_xw<128, 1><<<gM, 256, 0, stream>>>(bufB, Wc, bc, out, n, NC);
}

// Round 3
// 719.326 us; speedup vs baseline: 1.1617x; 1.0130x over previous
//
#include <hip/hip_runtime.h>
#include <hip/hip_bf16.h>

// ---------------------------------------------------------------------------
// GCN: out = relu(Agg(x@W1)+b1) -> relu(Agg(.@W2)+b2) -> .@Wc+bc
// Agg(h)[i] = dinv[i]^2*h[i] + sum_{e: dst=i} dinv[i]*dinv[src]*h[src]
// CSR built on-device each launch.
// R1: agg edge-loop unrolled x4 (latency-bound fix).
// R2: k_scatter was 130us with 105MB WRITE (16x line amplification: random
//     4B writes to 6.4MB from 8 non-coherent XCD L2s ping-pong every line).
//     -> XCD-sharded counting sort: shard=(edge>>8)&7 == blockIdx&7 matches
//     round-robin block->XCD dispatch, so each shard's write region stays in
//     one XCD's L2. Node-parallel compact merges shards into final CSR.
// ---------------------------------------------------------------------------

// ------------------------- preprocessing kernels ---------------------------

// per-(shard,node) histogram; shard = (edge>>8)&7 = blockIdx&7 (uniform/block)
__global__ __launch_bounds__(256) void k_deg8(const int* __restrict__ dst,
                                              int* __restrict__ deg8,
                                              int n, int E) {
    int i = blockIdx.x * 256 + threadIdx.x;
    if (i < E) {
        int s = (i >> 8) & 7;
        atomicAdd(&deg8[s * n + dst[i]], 1);
    }
}

// deg[i] = sum_s deg8[s][i]; dinv = rsqrt(deg+1)
__global__ __launch_bounds__(256) void k_degsum(const int* __restrict__ deg8,
                                                int* __restrict__ deg,
                                                float* __restrict__ dinv, int n) {
    int i = blockIdx.x * 256 + threadIdx.x;
    if (i < n) {
        int d = 0;
        #pragma unroll
        for (int s = 0; s < 8; ++s) d += deg8[s * n + i];
        deg[i] = d;
        dinv[i] = rsqrtf((float)(d + 1));
    }
}

__device__ inline int block_incl_scan_256(int t, int* tmp) {
    int tid = threadIdx.x;
    tmp[tid] = t;
    __syncthreads();
    #pragma unroll
    for (int off = 1; off < 256; off <<= 1) {
        int v = (tid >= off) ? tmp[tid - off] : 0;
        __syncthreads();
        tmp[tid] += v;
        __syncthreads();
    }
    return tmp[tid];
}

// chunk of 256*ITEMS elems per block
template <int ITEMS>
__global__ __launch_bounds__(256) void k_scan1(const int* __restrict__ v,
                                               int* __restrict__ bsum, int n) {
    __shared__ int tmp[256];
    int base = blockIdx.x * (256 * ITEMS) + threadIdx.x * ITEMS;
    int t = 0;
    #pragma unroll
    for (int l = 0; l < ITEMS; ++l) {
        int i = base + l;
        t += (i < n) ? v[i] : 0;
    }
    block_incl_scan_256(t, tmp);
    if (threadIdx.x == 0) bsum[blockIdx.x] = tmp[255];
}

__global__ __launch_bounds__(256) void k_scan2(int* __restrict__ bsum, int nb) {
    __shared__ int tmp[256];
    int tid = threadIdx.x;
    int v = (tid < nb) ? bsum[tid] : 0;
    block_incl_scan_256(v, tmp);
    if (tid < nb) bsum[tid] = tid ? tmp[tid - 1] : 0;
}

template <int ITEMS>
__global__ __launch_bounds__(256) void k_scan3(const int* __restrict__ vin,
                                               const int* __restrict__ bsum,
                                               int* __restrict__ rp, int n) {
    __shared__ int tmp[256];
    int base = blockIdx.x * (256 * ITEMS) + threadIdx.x * ITEMS;
    int v[ITEMS];
    int t = 0;
    #pragma unroll
    for (int l = 0; l < ITEMS; ++l) {
        int i = base + l;
        v[l] = (i < n) ? vin[i] : 0;
        t += v[l];
    }
    block_incl_scan_256(t, tmp);
    int run = bsum[blockIdx.x] + (threadIdx.x ? tmp[threadIdx.x - 1] : 0);
    #pragma unroll
    for (int l = 0; l < ITEMS; ++l) {
        int i = base + l;
        if (i < n) rp[i] = run;
        run += v[l];
    }
}

__global__ __launch_bounds__(256) void k_cursor8(const int* __restrict__ rowptr8,
                                                 int* __restrict__ cursor8,
                                                 int* __restrict__ rowptr8_end,
                                                 int* __restrict__ rowptr_end,
                                                 int m, int E) {
    int i = blockIdx.x * 256 + threadIdx.x;
    if (i < m) cursor8[i] = rowptr8[i];
    if (i == 0) { rowptr8_end[0] = E; rowptr_end[0] = E; }
}

__global__ __launch_bounds__(256) void k_scatter8(const int* __restrict__ src,
                                                  const int* __restrict__ dst,
                                                  int* __restrict__ cursor8,
                                                  int* __restrict__ col8,
                                                  int n, int E) {
    int i = blockIdx.x * 256 + threadIdx.x;
    if (i < E) {
        int s = (i >> 8) & 7;
        int d = dst[i];
        int p = atomicAdd(&cursor8[s * n + d], 1);
        col8[p] = src[i];
    }
}

// merge 8 shard segments of node i into final node-major CSR colArr
__global__ __launch_bounds__(256) void k_compact(const int* __restrict__ rowptr8,
                                                 const int* __restrict__ col8,
                                                 const int* __restrict__ rowptr,
                                                 int* __restrict__ colArr, int n) {
    int i = blockIdx.x * 256 + threadIdx.x;
    if (i >= n) return;
    int p = rowptr[i];
    #pragma unroll
    for (int s = 0; s < 8; ++s) {
        int a = rowptr8[s * n + i];
        int b = rowptr8[s * n + i + 1];
        for (int e = a; e < b; ++e) colArr[p++] = col8[e];
    }
}

// ------------------------------- GEMM --------------------------------------
// C[M,N] = A[M,K] @ W[K,N] (+bias). BM=64, BK=32, BN = 64*NCOL4.

template <int K, int NCOL4>
__global__ __launch_bounds__(256) void gemm_xw(const float* __restrict__ A,
                                               const float* __restrict__ W,
                                               const float* __restrict__ bias,
                                               float* __restrict__ C,
                                               int M, int N) {
    constexpr int BK = 32;
    constexpr int BN = 64 * NCOL4;
    __shared__ __align__(16) float xs[BK][68];
    __shared__ __align__(16) float ws[BK][BN];

    const int tid = threadIdx.x;
    const int bm  = blockIdx.x * 64;
    const int cg  = tid & 15;
    const int rg  = tid >> 4;
    const int r0  = rg * 4;
    const int c0  = cg * 4;

    float acc[4][NCOL4 * 4];
    #pragma unroll
    for (int r = 0; r < 4; ++r)
        #pragma unroll
        for (int j = 0; j < NCOL4 * 4; ++j) acc[r][j] = 0.f;

    for (int k0 = 0; k0 < K; k0 += BK) {
        #pragma unroll
        for (int l = 0; l < 2; ++l) {
            int f4  = tid + l * 256;
            int row = f4 >> 3;
            int kk  = (f4 & 7) << 2;
            float4 v = make_float4(0.f, 0.f, 0.f, 0.f);
            int grow = bm + row;
            if (grow < M)
                v = *(const float4*)(A + (size_t)grow * K + k0 + kk);
            xs[kk + 0][row] = v.x;
            xs[kk + 1][row] = v.y;
            xs[kk + 2][row] = v.z;
            xs[kk + 3][row] = v.w;
        }
        if (NCOL4 == 2) {
            #pragma unroll
            for (int l = 0; l < 4; ++l) {
                int idx = tid + l * 256;
                int kk  = idx >> 5;
                int cc  = (idx & 31) << 2;
                *(float4*)&ws[kk][cc] =
                    *(const float4*)(W + (size_t)(k0 + kk) * N + cc);
            }
        } else {
            #pragma unroll
            for (int l = 0; l < 8; ++l) {
                int idx = tid + l * 256;
                int kk  = idx >> 6;
                int cc  = idx & 63;
                ws[kk][cc] = (cc < N) ? W[(size_t)(k0 + kk) * N + cc] : 0.f;
            }
        }
        __syncthreads();

        #pragma unroll
        for (int kk = 0; kk < BK; ++kk) {
            float4 xv = *(const float4*)&xs[kk][r0];
            float4 w0 = *(const float4*)&ws[kk][c0];
            float4 w1 = (NCOL4 == 2) ? *(const float4*)&ws[kk][c0 + 64]
                                     : make_float4(0.f, 0.f, 0.f, 0.f);
            float xr[4] = {xv.x, xv.y, xv.z, xv.w};
            #pragma unroll
            for (int r = 0; r < 4; ++r) {
                acc[r][0] += xr[r] * w0.x;
                acc[r][1] += xr[r] * w0.y;
                acc[r][2] += xr[r] * w0.z;
                acc[r][3] += xr[r] * w0.w;
                if (NCOL4 == 2) {
                    acc[r][4] += xr[r] * w1.x;
                    acc[r][5] += xr[r] * w1.y;
                    acc[r][6] += xr[r] * w1.z;
                    acc[r][7] += xr[r] * w1.w;
                }
            }
        }
        __syncthreads();
    }

    #pragma unroll
    for (int r = 0; r < 4; ++r) {
        int grow = bm + r0 + r;
        if (grow >= M) continue;
        #pragma unroll
        for (int g = 0; g < NCOL4; ++g) {
            int cc = c0 + g * 64;
            if (cc >= N) continue;
            float4 o;
            o.x = acc[r][g * 4 + 0];
            o.y = acc[r][g * 4 + 1];
            o.z = acc[r][g * 4 + 2];
            o.w = acc[r][g * 4 + 3];
            if (bias) {
                o.x += bias[cc + 0];
                o.y += bias[cc + 1];
                o.z += bias[cc + 2];
                o.w += bias[cc + 3];
            }
            *(float4*)(C + (size_t)grow * N + cc) = o;
        }
    }
}

// ---------------------------- aggregation ----------------------------------
// One wave per node; lane covers 2 cols (float2). Edge loop unrolled x4.

__global__ __launch_bounds__(256) void gcn_agg(const float* __restrict__ h,
                                               const int* __restrict__ rowptr,
                                               const int* __restrict__ colArr,
                                               const float* __restrict__ dinv,
                                               const float* __restrict__ bias,
                                               float* __restrict__ out,
                                               int n, int do_relu) {
    int node = blockIdx.x * 4 + (threadIdx.x >> 6);
    if (node >= n) return;
    int lane = threadIdx.x & 63;
    const float2* __restrict__ hp = (const float2*)h;

    float di = dinv[node];
    float2 v = hp[(size_t)node * 64 + lane];
    float s  = di * di;
    float accx = v.x * s;
    float accy = v.y * s;

    int e0 = rowptr[node];
    int e1 = rowptr[node + 1];
    int e  = e0;

    for (; e + 4 <= e1; e += 4) {
        int j0 = colArr[e + 0];
        int j1 = colArr[e + 1];
        int j2 = colArr[e + 2];
        int j3 = colArr[e + 3];
        float w0 = dinv[j0];
        float w1 = dinv[j1];
        float w2 = dinv[j2];
        float w3 = dinv[j3];
        float2 u0 = hp[(size_t)j0 * 64 + lane];
        float2 u1 = hp[(size_t)j1 * 64 + lane];
        float2 u2 = hp[(size_t)j2 * 64 + lane];
        float2 u3 = hp[(size_t)j3 * 64 + lane];
        w0 *= di; w1 *= di; w2 *= di; w3 *= di;
        accx += u0.x * w0;
        accy += u0.y * w0;
        accx += u1.x * w1;
        accy += u1.y * w1;
        accx += u2.x * w2;
        accy += u2.y * w2;
        accx += u3.x * w3;
        accy += u3.y * w3;
    }
    for (; e < e1; ++e) {
        int j = colArr[e];
        float w = di * dinv[j];
        float2 u = hp[(size_t)j * 64 + lane];
        accx += u.x * w;
        accy += u.y * w;
    }

    float2 b = ((const float2*)bias)[lane];
    float ox = accx + b.x;
    float oy = accy + b.y;
    if (do_relu) {
        ox = fmaxf(ox, 0.f);
        oy = fmaxf(oy, 0.f);
    }
    ((float2*)(out + (size_t)node * 128))[lane] = make_float2(ox, oy);
}

// ------------------------------- launch ------------------------------------

extern "C" void kernel_launch(void* const* d_in, const int* in_sizes, int n_in,
                              void* d_out, int out_size, void* d_ws, size_t ws_size,
                              hipStream_t stream) {
    const float* x  = (const float*)d_in[0];
    const int* eidx = (const int*)d_in[1];
    const float* W1 = (const float*)d_in[2];
    const float* b1 = (const float*)d_in[3];
    const float* W2 = (const float*)d_in[4];
    const float* b2 = (const float*)d_in[5];
    const float* Wc = (const float*)d_in[6];
    const float* bc = (const float*)d_in[7];
    float* out = (float*)d_out;

    const int NF = 256, NH = 128, NC = 40;
    const int n = in_sizes[0] / NF;    // 100000
    const int E = in_sizes[1] / 2;     // 1600000
    const int m = 8 * n;               // sharded histogram size
    const int* src = eidx;
    const int* dst = eidx + E;

    char* wsb = (char*)d_ws;
    size_t off = 0;
    auto alloc = [&](size_t bytes) {
        char* p = wsb + off;
        off = (off + bytes + 511) & ~(size_t)511;
        return p;
    };
    float* bufA   = (float*)alloc((size_t)n * NH * 4);   // 51.2 MB
    float* bufB   = (float*)alloc((size_t)n * NH * 4);   // 51.2 MB
    int* colArr   = (int*)alloc((size_t)E * 4);          // 6.4 MB
    int* col8     = (int*)alloc((size_t)E * 4);          // 6.4 MB
    int* deg8     = (int*)alloc((size_t)m * 4);          // 3.2 MB
    int* rowptr8  = (int*)alloc((size_t)(m + 1) * 4);
    int* cursor8  = (int*)alloc((size_t)m * 4);
    int* deg      = (int*)alloc((size_t)n * 4);
    int* rowptr   = (int*)alloc((size_t)(n + 1) * 4);
    float* dinv   = (float*)alloc((size_t)n * 4);
    int* bsumA    = (int*)alloc(1024);
    int* bsumB    = (int*)alloc(1024);

    const int gE  = (E + 255) / 256;
    const int gN  = (n + 255) / 256;
    const int gM8 = (m + 255) / 256;
    const int nbA = (m + 4095) / 4096;   // 196 <= 256
    const int nbB = (n + 1023) / 1024;   // 98  <= 256

    hipMemsetAsync(deg8, 0, (size_t)m * 4, stream);
    k_deg8<<<gE, 256, 0, stream>>>(dst, deg8, n, E);
    k_degsum<<<gN, 256, 0, stream>>>(deg8, deg, dinv, n);
    k_scan1<16><<<nbA, 256, 0, stream>>>(deg8, bsumA, m);
    k_scan2<<<1, 256, 0, stream>>>(bsumA, nbA);
    k_scan3<16><<<nbA, 256, 0, stream>>>(deg8, bsumA, rowptr8, m);
    k_scan1<4><<<nbB, 256, 0, stream>>>(deg, bsumB, n);
    k_scan2<<<1, 256, 0, stream>>>(bsumB, nbB);
    k_scan3<4><<<nbB, 256, 0, stream>>>(deg, bsumB, rowptr, n);
    k_cursor8<<<gM8, 256, 0, stream>>>(rowptr8, cursor8, rowptr8 + m, rowptr + n, m, E);
    k_scatter8<<<gE, 256, 0, stream>>>(src, dst, cursor8, col8, n, E);
    k_compact<<<gN, 256, 0, stream>>>(rowptr8, col8, rowptr, colArr, n);

    const int gMt = (n + 63) / 64;
    gemm_xw<256, 2><<<gMt, 256, 0, stream>>>(x, W1, nullptr, bufA, n, NH);
    gcn_agg<<<(n + 3) / 4, 256, 0, stream>>>(bufA, rowptr, colArr, dinv, b1, bufB, n, 1);
    gemm_xw<128, 2><<<gMt, 256, 0, stream>>>(bufB, W2, nullptr, bufA, n, NH);
    gcn_agg<<<(n + 3) / 4, 256, 0, stream>>>(bufA, rowptr, colArr, dinv, b2, bufB, n, 1);
    gemm_xw<128, 1><<<gMt, 256, 0, stream>>>(bufB, Wc, bc, out, n, NC);
}

// Round 4
// 647.046 us; speedup vs baseline: 1.2915x; 1.1117x over previous
//
#include <hip/hip_runtime.h>
#include <hip/hip_bf16.h>
#include <type_traits>

// ---------------------------------------------------------------------------
// GCN: out = relu(Agg(x@W1)+b1) -> relu(Agg(.@W2)+b2) -> .@Wc+bc
// Agg(h)[i] = dinv[i]^2*h[i] + sum_{e: dst=i} dinv[i]*dinv[src]*h[src]
// R1: agg edge-loop unrolled x4 (latency fix: 178->123us... with R2).
// R2: XCD-sharded counting sort (k_scatter 130us/105MB-write -> ~15us).
// R3: agg is L2-miss-BW-bound (FETCH 415MB vs 819MB logical, pinned at
//     3.87 TB/s). -> store h1/h2 as bf16: gather row 512B->256B. Compute
//     stays fp32 (agg accumulates fp32, GEMM inputs a1/a2 stay fp32).
// ---------------------------------------------------------------------------

static __device__ __forceinline__ unsigned short f2bf(float f) {
    unsigned int u = __float_as_uint(f);
    u = (u + 0x7fffu + ((u >> 16) & 1u)) >> 16;   // round-to-nearest-even
    return (unsigned short)u;
}

// ------------------------- preprocessing kernels ---------------------------

__global__ __launch_bounds__(256) void k_deg8(const int* __restrict__ dst,
                                              int* __restrict__ deg8,
                                              int n, int E) {
    int i = blockIdx.x * 256 + threadIdx.x;
    if (i < E) {
        int s = (i >> 8) & 7;
        atomicAdd(&deg8[s * n + dst[i]], 1);
    }
}

__global__ __launch_bounds__(256) void k_degsum(const int* __restrict__ deg8,
                                                int* __restrict__ deg,
                                                float* __restrict__ dinv, int n) {
    int i = blockIdx.x * 256 + threadIdx.x;
    if (i < n) {
        int d = 0;
        #pragma unroll
        for (int s = 0; s < 8; ++s) d += deg8[s * n + i];
        deg[i] = d;
        dinv[i] = rsqrtf((float)(d + 1));
    }
}

__device__ inline int block_incl_scan_256(int t, int* tmp) {
    int tid = threadIdx.x;
    tmp[tid] = t;
    __syncthreads();
    #pragma unroll
    for (int off = 1; off < 256; off <<= 1) {
        int v = (tid >= off) ? tmp[tid - off] : 0;
        __syncthreads();
        tmp[tid] += v;
        __syncthreads();
    }
    return tmp[tid];
}

template <int ITEMS>
__global__ __launch_bounds__(256) void k_scan1(const int* __restrict__ v,
                                               int* __restrict__ bsum, int n) {
    __shared__ int tmp[256];
    int base = blockIdx.x * (256 * ITEMS) + threadIdx.x * ITEMS;
    int t = 0;
    #pragma unroll
    for (int l = 0; l < ITEMS; ++l) {
        int i = base + l;
        t += (i < n) ? v[i] : 0;
    }
    block_incl_scan_256(t, tmp);
    if (threadIdx.x == 0) bsum[blockIdx.x] = tmp[255];
}

__global__ __launch_bounds__(256) void k_scan2(int* __restrict__ bsum, int nb) {
    __shared__ int tmp[256];
    int tid = threadIdx.x;
    int v = (tid < nb) ? bsum[tid] : 0;
    block_incl_scan_256(v, tmp);
    if (tid < nb) bsum[tid] = tid ? tmp[tid - 1] : 0;
}

template <int ITEMS>
__global__ __launch_bounds__(256) void k_scan3(const int* __restrict__ vin,
                                               const int* __restrict__ bsum,
                                               int* __restrict__ rp, int n) {
    __shared__ int tmp[256];
    int base = blockIdx.x * (256 * ITEMS) + threadIdx.x * ITEMS;
    int v[ITEMS];
    int t = 0;
    #pragma unroll
    for (int l = 0; l < ITEMS; ++l) {
        int i = base + l;
        v[l] = (i < n) ? vin[i] : 0;
        t += v[l];
    }
    block_incl_scan_256(t, tmp);
    int run = bsum[blockIdx.x] + (threadIdx.x ? tmp[threadIdx.x - 1] : 0);
    #pragma unroll
    for (int l = 0; l < ITEMS; ++l) {
        int i = base + l;
        if (i < n) rp[i] = run;
        run += v[l];
    }
}

__global__ __launch_bounds__(256) void k_cursor8(const int* __restrict__ rowptr8,
                                                 int* __restrict__ cursor8,
                                                 int* __restrict__ rowptr8_end,
                                                 int* __restrict__ rowptr_end,
                                                 int m, int E) {
    int i = blockIdx.x * 256 + threadIdx.x;
    if (i < m) cursor8[i] = rowptr8[i];
    if (i == 0) { rowptr8_end[0] = E; rowptr_end[0] = E; }
}

__global__ __launch_bounds__(256) void k_scatter8(const int* __restrict__ src,
                                                  const int* __restrict__ dst,
                                                  int* __restrict__ cursor8,
                                                  int* __restrict__ col8,
                                                  int n, int E) {
    int i = blockIdx.x * 256 + threadIdx.x;
    if (i < E) {
        int s = (i >> 8) & 7;
        int d = dst[i];
        int p = atomicAdd(&cursor8[s * n + d], 1);
        col8[p] = src[i];
    }
}

__global__ __launch_bounds__(256) void k_compact(const int* __restrict__ rowptr8,
                                                 const int* __restrict__ col8,
                                                 const int* __restrict__ rowptr,
                                                 int* __restrict__ colArr, int n) {
    int i = blockIdx.x * 256 + threadIdx.x;
    if (i >= n) return;
    int p = rowptr[i];
    #pragma unroll
    for (int s = 0; s < 8; ++s) {
        int a = rowptr8[s * n + i];
        int b = rowptr8[s * n + i + 1];
        for (int e = a; e < b; ++e) colArr[p++] = col8[e];
    }
}

// ------------------------------- GEMM --------------------------------------
// C[M,N] = A[M,K] @ W[K,N] (+bias). BM=64, BK=32, BN = 64*NCOL4.
// OutT = __hip_bfloat16 (h1/h2, halves write + later gather traffic) or float.

template <int K, int NCOL4, typename OutT>
__global__ __launch_bounds__(256) void gemm_xw(const float* __restrict__ A,
                                               const float* __restrict__ W,
                                               const float* __restrict__ bias,
                                               OutT* __restrict__ C,
                                               int M, int N) {
    constexpr int BK = 32;
    constexpr int BN = 64 * NCOL4;
    __shared__ __align__(16) float xs[BK][68];
    __shared__ __align__(16) float ws[BK][BN];

    const int tid = threadIdx.x;
    const int bm  = blockIdx.x * 64;
    const int cg  = tid & 15;
    const int rg  = tid >> 4;
    const int r0  = rg * 4;
    const int c0  = cg * 4;

    float acc[4][NCOL4 * 4];
    #pragma unroll
    for (int r = 0; r < 4; ++r)
        #pragma unroll
        for (int j = 0; j < NCOL4 * 4; ++j) acc[r][j] = 0.f;

    for (int k0 = 0; k0 < K; k0 += BK) {
        #pragma unroll
        for (int l = 0; l < 2; ++l) {
            int f4  = tid + l * 256;
            int row = f4 >> 3;
            int kk  = (f4 & 7) << 2;
            float4 v = make_float4(0.f, 0.f, 0.f, 0.f);
            int grow = bm + row;
            if (grow < M)
                v = *(const float4*)(A + (size_t)grow * K + k0 + kk);
            xs[kk + 0][row] = v.x;
            xs[kk + 1][row] = v.y;
            xs[kk + 2][row] = v.z;
            xs[kk + 3][row] = v.w;
        }
        if (NCOL4 == 2) {
            #pragma unroll
            for (int l = 0; l < 4; ++l) {
                int idx = tid + l * 256;
                int kk  = idx >> 5;
                int cc  = (idx & 31) << 2;
                *(float4*)&ws[kk][cc] =
                    *(const float4*)(W + (size_t)(k0 + kk) * N + cc);
            }
        } else {
            #pragma unroll
            for (int l = 0; l < 8; ++l) {
                int idx = tid + l * 256;
                int kk  = idx >> 6;
                int cc  = idx & 63;
                ws[kk][cc] = (cc < N) ? W[(size_t)(k0 + kk) * N + cc] : 0.f;
            }
        }
        __syncthreads();

        #pragma unroll
        for (int kk = 0; kk < BK; ++kk) {
            float4 xv = *(const float4*)&xs[kk][r0];
            float4 w0 = *(const float4*)&ws[kk][c0];
            float4 w1 = (NCOL4 == 2) ? *(const float4*)&ws[kk][c0 + 64]
                                     : make_float4(0.f, 0.f, 0.f, 0.f);
            float xr[4] = {xv.x, xv.y, xv.z, xv.w};
            #pragma unroll
            for (int r = 0; r < 4; ++r) {
                acc[r][0] += xr[r] * w0.x;
                acc[r][1] += xr[r] * w0.y;
                acc[r][2] += xr[r] * w0.z;
                acc[r][3] += xr[r] * w0.w;
                if (NCOL4 == 2) {
                    acc[r][4] += xr[r] * w1.x;
                    acc[r][5] += xr[r] * w1.y;
                    acc[r][6] += xr[r] * w1.z;
                    acc[r][7] += xr[r] * w1.w;
                }
            }
        }
        __syncthreads();
    }

    #pragma unroll
    for (int r = 0; r < 4; ++r) {
        int grow = bm + r0 + r;
        if (grow >= M) continue;
        #pragma unroll
        for (int g = 0; g < NCOL4; ++g) {
            int cc = c0 + g * 64;
            if (cc >= N) continue;
            float o0 = acc[r][g * 4 + 0];
            float o1 = acc[r][g * 4 + 1];
            float o2 = acc[r][g * 4 + 2];
            float o3 = acc[r][g * 4 + 3];
            if (bias) {
                o0 += bias[cc + 0];
                o1 += bias[cc + 1];
                o2 += bias[cc + 2];
                o3 += bias[cc + 3];
            }
            if constexpr (std::is_same<OutT, float>::value) {
                float4 o = make_float4(o0, o1, o2, o3);
                *(float4*)((float*)C + (size_t)grow * N + cc) = o;
            } else {
                uint2 p;
                p.x = (unsigned)f2bf(o0) | ((unsigned)f2bf(o1) << 16);
                p.y = (unsigned)f2bf(o2) | ((unsigned)f2bf(o3) << 16);
                *(uint2*)((unsigned short*)C + (size_t)grow * N + cc) = p;
            }
        }
    }
}

// ---------------------------- aggregation ----------------------------------
// One wave per node; lane covers 2 cols. h is bf16 [n,128]: lane reads one
// uint (2 bf16) -> 256 B/row gather (was 512 B fp32). Compute fp32; output
// a (fp32) feeds the next GEMM at full precision. Edge loop unrolled x4.

static __device__ __forceinline__ float2 bf2x(unsigned int raw) {
    float2 r;
    r.x = __uint_as_float(raw << 16);
    r.y = __uint_as_float(raw & 0xffff0000u);
    return r;
}

__global__ __launch_bounds__(256) void gcn_agg(const unsigned int* __restrict__ h,
                                               const int* __restrict__ rowptr,
                                               const int* __restrict__ colArr,
                                               const float* __restrict__ dinv,
                                               const float* __restrict__ bias,
                                               float* __restrict__ out,
                                               int n, int do_relu) {
    int node = blockIdx.x * 4 + (threadIdx.x >> 6);
    if (node >= n) return;
    int lane = threadIdx.x & 63;

    float di = dinv[node];
    float2 v = bf2x(h[(size_t)node * 64 + lane]);
    float s  = di * di;
    float accx = v.x * s;
    float accy = v.y * s;

    int e0 = rowptr[node];
    int e1 = rowptr[node + 1];
    int e  = e0;

    for (; e + 4 <= e1; e += 4) {
        int j0 = colArr[e + 0];
        int j1 = colArr[e + 1];
        int j2 = colArr[e + 2];
        int j3 = colArr[e + 3];
        float w0 = dinv[j0];
        float w1 = dinv[j1];
        float w2 = dinv[j2];
        float w3 = dinv[j3];
        unsigned int r0 = h[(size_t)j0 * 64 + lane];
        unsigned int r1 = h[(size_t)j1 * 64 + lane];
        unsigned int r2 = h[(size_t)j2 * 64 + lane];
        unsigned int r3 = h[(size_t)j3 * 64 + lane];
        w0 *= di; w1 *= di; w2 *= di; w3 *= di;
        float2 u0 = bf2x(r0);
        float2 u1 = bf2x(r1);
        float2 u2 = bf2x(r2);
        float2 u3 = bf2x(r3);
        accx += u0.x * w0;
        accy += u0.y * w0;
        accx += u1.x * w1;
        accy += u1.y * w1;
        accx += u2.x * w2;
        accy += u2.y * w2;
        accx += u3.x * w3;
        accy += u3.y * w3;
    }
    for (; e < e1; ++e) {
        int j = colArr[e];
        float w = di * dinv[j];
        float2 u = bf2x(h[(size_t)j * 64 + lane]);
        accx += u.x * w;
        accy += u.y * w;
    }

    float2 b = ((const float2*)bias)[lane];
    float ox = accx + b.x;
    float oy = accy + b.y;
    if (do_relu) {
        ox = fmaxf(ox, 0.f);
        oy = fmaxf(oy, 0.f);
    }
    ((float2*)(out + (size_t)node * 128))[lane] = make_float2(ox, oy);
}

// ------------------------------- launch ------------------------------------

extern "C" void kernel_launch(void* const* d_in, const int* in_sizes, int n_in,
                              void* d_out, int out_size, void* d_ws, size_t ws_size,
                              hipStream_t stream) {
    const float* x  = (const float*)d_in[0];
    const int* eidx = (const int*)d_in[1];
    const float* W1 = (const float*)d_in[2];
    const float* b1 = (const float*)d_in[3];
    const float* W2 = (const float*)d_in[4];
    const float* b2 = (const float*)d_in[5];
    const float* Wc = (const float*)d_in[6];
    const float* bc = (const float*)d_in[7];
    float* out = (float*)d_out;

    const int NF = 256, NH = 128, NC = 40;
    const int n = in_sizes[0] / NF;    // 100000
    const int E = in_sizes[1] / 2;     // 1600000
    const int m = 8 * n;
    const int* src = eidx;
    const int* dst = eidx + E;

    char* wsb = (char*)d_ws;
    size_t off = 0;
    auto alloc = [&](size_t bytes) {
        char* p = wsb + off;
        off = (off + bytes + 511) & ~(size_t)511;
        return p;
    };
    __hip_bfloat16* hbuf = (__hip_bfloat16*)alloc((size_t)n * NH * 2);  // 25.6 MB
    float* abuf   = (float*)alloc((size_t)n * NH * 4);                  // 51.2 MB
    int* colArr   = (int*)alloc((size_t)E * 4);
    int* col8     = (int*)alloc((size_t)E * 4);
    int* deg8     = (int*)alloc((size_t)m * 4);
    int* rowptr8  = (int*)alloc((size_t)(m + 1) * 4);
    int* cursor8  = (int*)alloc((size_t)m * 4);
    int* deg      = (int*)alloc((size_t)n * 4);
    int* rowptr   = (int*)alloc((size_t)(n + 1) * 4);
    float* dinv   = (float*)alloc((size_t)n * 4);
    int* bsumA    = (int*)alloc(1024);
    int* bsumB    = (int*)alloc(1024);

    const int gE  = (E + 255) / 256;
    const int gN  = (n + 255) / 256;
    const int gM8 = (m + 255) / 256;
    const int nbA = (m + 4095) / 4096;
    const int nbB = (n + 1023) / 1024;

    hipMemsetAsync(deg8, 0, (size_t)m * 4, stream);
    k_deg8<<<gE, 256, 0, stream>>>(dst, deg8, n, E);
    k_degsum<<<gN, 256, 0, stream>>>(deg8, deg, dinv, n);
    k_scan1<16><<<nbA, 256, 0, stream>>>(deg8, bsumA, m);
    k_scan2<<<1, 256, 0, stream>>>(bsumA, nbA);
    k_scan3<16><<<nbA, 256, 0, stream>>>(deg8, bsumA, rowptr8, m);
    k_scan1<4><<<nbB, 256, 0, stream>>>(deg, bsumB, n);
    k_scan2<<<1, 256, 0, stream>>>(bsumB, nbB);
    k_scan3<4><<<nbB, 256, 0, stream>>>(deg, bsumB, rowptr, n);
    k_cursor8<<<gM8, 256, 0, stream>>>(rowptr8, cursor8, rowptr8 + m, rowptr + n, m, E);
    k_scatter8<<<gE, 256, 0, stream>>>(src, dst, cursor8, col8, n, E);
    k_compact<<<gN, 256, 0, stream>>>(rowptr8, col8, rowptr, colArr, n);

    const int gMt = (n + 63) / 64;
    gemm_xw<256, 2, __hip_bfloat16><<<gMt, 256, 0, stream>>>(x, W1, nullptr, hbuf, n, NH);
    gcn_agg<<<(n + 3) / 4, 256, 0, stream>>>((const unsigned int*)hbuf, rowptr, colArr, dinv, b1, abuf, n, 1);
    gemm_xw<128, 2, __hip_bfloat16><<<gMt, 256, 0, stream>>>(abuf, W2, nullptr, hbuf, n, NH);
    gcn_agg<<<(n + 3) / 4, 256, 0, stream>>>((const unsigned int*)hbuf, rowptr, colArr, dinv, b2, abuf, n, 1);
    gemm_xw<128, 1, float><<<gMt, 256, 0, stream>>>(abuf, Wc, bc, out, n, NC);
}

// Round 5
// 549.128 us; speedup vs baseline: 1.5218x; 1.1783x over previous
//
#include <hip/hip_runtime.h>
#include <hip/hip_bf16.h>
#include <hip/hip_fp16.h>
#include <type_traits>

// ---------------------------------------------------------------------------
// GCN: out = relu(Agg(x@W1)+b1) -> relu(Agg(.@W2)+b2) -> .@Wc+bc
// Agg(h)[i] = dinv[i]^2*h[i] + sum_{e: dst=i} dinv[i]*dinv[src]*h[src]
// R1: agg edge-loop unrolled x4 (latency fix).
// R2: XCD-sharded counting sort (k_scatter 130us/105MB-write -> ~15us).
// R3: h intermediates 2-byte: gather row 512B->256B (agg 123->~70us).
// R4: fp32 vector GEMM was 33% of 157TF VALU peak (126us GEMM1, MfmaUtil=0).
//     -> v_mfma_f32_16x16x32_f16 for all 3 GEMMs, fp16 inputs/fp32 acc.
//     h/a buffers bf16->fp16 (4x better mantissa pays for GEMM input casts).
//     W pre-transposed+cast to [N][K] fp16 once (k_wcast) so B-frags are
//     k-contiguous ds_read_b128. LDS stride 40 halfs -> <=2-way banks.
// ---------------------------------------------------------------------------

typedef _Float16 half8 __attribute__((ext_vector_type(8)));
typedef _Float16 half4v __attribute__((ext_vector_type(4)));
typedef float floatx4 __attribute__((ext_vector_type(4)));

// ------------------------- preprocessing kernels ---------------------------

__global__ __launch_bounds__(256) void k_deg8(const int* __restrict__ dst,
                                              int* __restrict__ deg8,
                                              int n, int E) {
    int i = blockIdx.x * 256 + threadIdx.x;
    if (i < E) {
        int s = (i >> 8) & 7;
        atomicAdd(&deg8[s * n + dst[i]], 1);
    }
}

__global__ __launch_bounds__(256) void k_degsum(const int* __restrict__ deg8,
                                                int* __restrict__ deg,
                                                float* __restrict__ dinv, int n) {
    int i = blockIdx.x * 256 + threadIdx.x;
    if (i < n) {
        int d = 0;
        #pragma unroll
        for (int s = 0; s < 8; ++s) d += deg8[s * n + i];
        deg[i] = d;
        dinv[i] = rsqrtf((float)(d + 1));
    }
}

__device__ inline int block_incl_scan_256(int t, int* tmp) {
    int tid = threadIdx.x;
    tmp[tid] = t;
    __syncthreads();
    #pragma unroll
    for (int off = 1; off < 256; off <<= 1) {
        int v = (tid >= off) ? tmp[tid - off] : 0;
        __syncthreads();
        tmp[tid] += v;
        __syncthreads();
    }
    return tmp[tid];
}

template <int ITEMS>
__global__ __launch_bounds__(256) void k_scan1(const int* __restrict__ v,
                                               int* __restrict__ bsum, int n) {
    __shared__ int tmp[256];
    int base = blockIdx.x * (256 * ITEMS) + threadIdx.x * ITEMS;
    int t = 0;
    #pragma unroll
    for (int l = 0; l < ITEMS; ++l) {
        int i = base + l;
        t += (i < n) ? v[i] : 0;
    }
    block_incl_scan_256(t, tmp);
    if (threadIdx.x == 0) bsum[blockIdx.x] = tmp[255];
}

__global__ __launch_bounds__(256) void k_scan2(int* __restrict__ bsum, int nb) {
    __shared__ int tmp[256];
    int tid = threadIdx.x;
    int v = (tid < nb) ? bsum[tid] : 0;
    block_incl_scan_256(v, tmp);
    if (tid < nb) bsum[tid] = tid ? tmp[tid - 1] : 0;
}

template <int ITEMS>
__global__ __launch_bounds__(256) void k_scan3(const int* __restrict__ vin,
                                               const int* __restrict__ bsum,
                                               int* __restrict__ rp, int n) {
    __shared__ int tmp[256];
    int base = blockIdx.x * (256 * ITEMS) + threadIdx.x * ITEMS;
    int v[ITEMS];
    int t = 0;
    #pragma unroll
    for (int l = 0; l < ITEMS; ++l) {
        int i = base + l;
        v[l] = (i < n) ? vin[i] : 0;
        t += v[l];
    }
    block_incl_scan_256(t, tmp);
    int run = bsum[blockIdx.x] + (threadIdx.x ? tmp[threadIdx.x - 1] : 0);
    #pragma unroll
    for (int l = 0; l < ITEMS; ++l) {
        int i = base + l;
        if (i < n) rp[i] = run;
        run += v[l];
    }
}

__global__ __launch_bounds__(256) void k_cursor8(const int* __restrict__ rowptr8,
                                                 int* __restrict__ cursor8,
                                                 int* __restrict__ rowptr8_end,
                                                 int* __restrict__ rowptr_end,
                                                 int m, int E) {
    int i = blockIdx.x * 256 + threadIdx.x;
    if (i < m) cursor8[i] = rowptr8[i];
    if (i == 0) { rowptr8_end[0] = E; rowptr_end[0] = E; }
}

__global__ __launch_bounds__(256) void k_scatter8(const int* __restrict__ src,
                                                  const int* __restrict__ dst,
                                                  int* __restrict__ cursor8,
                                                  int* __restrict__ col8,
                                                  int n, int E) {
    int i = blockIdx.x * 256 + threadIdx.x;
    if (i < E) {
        int s = (i >> 8) & 7;
        int d = dst[i];
        int p = atomicAdd(&cursor8[s * n + d], 1);
        col8[p] = src[i];
    }
}

__global__ __launch_bounds__(256) void k_compact(const int* __restrict__ rowptr8,
                                                 const int* __restrict__ col8,
                                                 const int* __restrict__ rowptr,
                                                 int* __restrict__ colArr, int n) {
    int i = blockIdx.x * 256 + threadIdx.x;
    if (i >= n) return;
    int p = rowptr[i];
    #pragma unroll
    for (int s = 0; s < 8; ++s) {
        int a = rowptr8[s * n + i];
        int b = rowptr8[s * n + i + 1];
        for (int e = a; e < b; ++e) colArr[p++] = col8[e];
    }
}

// W[K][N] fp32 -> Wt[NP][K] fp16, zero-padded for c in [N, NP). K pow2.
__global__ __launch_bounds__(256) void k_wcast(const float* __restrict__ W,
                                               _Float16* __restrict__ Wt,
                                               int N, int K, int kbits, int total) {
    int i = blockIdx.x * 256 + threadIdx.x;
    if (i < total) {
        int c = i >> kbits;
        int k = i & (K - 1);
        Wt[i] = (c < N) ? (_Float16)W[(size_t)k * N + c] : (_Float16)0.f;
    }
}

// ---------------------------- MFMA GEMM ------------------------------------
// C[M,N] = A[M,K] @ W[K,N] via v_mfma_f32_16x16x32_f16.
// Wt is pre-transposed [BN][K] fp16 (BN >= N, zero-padded).
// BM=64, BK=32, 256 thr = 4 waves; wave w owns rows [16w,16w+16) x BN cols.
// LDS tiles stride 40 halfs (80 B): b128 frag reads <=2-way bank aliasing.
// A/B frag layout (m89/m120-verified): operand[idx=lane&15][k=(lane>>4)*8+j];
// C/D: col=lane&15, row=(lane>>4)*4+reg.

template <int K, int BN, typename AT, typename OT>
__global__ __launch_bounds__(256) void gemm_mfma(const AT* __restrict__ A,
                                                 const _Float16* __restrict__ Wt,
                                                 const float* __restrict__ bias,
                                                 OT* __restrict__ C,
                                                 int M, int N) {
    constexpr int NT = BN / 16;
    __shared__ __align__(16) _Float16 As[64][40];
    __shared__ __align__(16) _Float16 Bs[BN][40];

    const int tid  = threadIdx.x;
    const int bm   = blockIdx.x * 64;
    const int lane = tid & 63;
    const int wv   = tid >> 6;
    const int qd   = lane >> 4;
    const int ln15 = lane & 15;

    floatx4 acc[NT];
    #pragma unroll
    for (int c = 0; c < NT; ++c) acc[c] = (floatx4){0.f, 0.f, 0.f, 0.f};

    for (int k0 = 0; k0 < K; k0 += 32) {
        // ---- stage A (64 x 32 halfs) ----
        if constexpr (std::is_same<AT, float>::value) {
            #pragma unroll
            for (int l = 0; l < 2; ++l) {
                int f4  = tid + l * 256;          // 0..511 float4 slots
                int row = f4 >> 3;
                int kk  = (f4 & 7) << 2;
                float4 v = make_float4(0.f, 0.f, 0.f, 0.f);
                if (bm + row < M)
                    v = *(const float4*)(A + (size_t)(bm + row) * K + k0 + kk);
                half4v h;
                h[0] = (_Float16)v.x; h[1] = (_Float16)v.y;
                h[2] = (_Float16)v.z; h[3] = (_Float16)v.w;
                *(half4v*)&As[row][kk] = h;
            }
        } else {
            int row = tid >> 2;
            int kk  = (tid & 3) << 3;             // 8-half groups
            uint4 v = make_uint4(0u, 0u, 0u, 0u);
            if (bm + row < M)
                v = *(const uint4*)((const _Float16*)A + (size_t)(bm + row) * K + k0 + kk);
            *(uint4*)&As[row][kk] = v;
        }
        // ---- stage B (BN x 32 halfs) from Wt[BN][K] ----
        #pragma unroll
        for (int l = 0; l < (BN * 4 + 255) / 256; ++l) {
            int idx = tid + l * 256;              // 8-half groups
            if (idx < BN * 4) {
                int col = idx >> 2;
                int kk  = (idx & 3) << 3;
                *(uint4*)&Bs[col][kk] =
                    *(const uint4*)(Wt + (size_t)col * K + k0 + kk);
            }
        }
        __syncthreads();

        half8 a = *(const half8*)&As[wv * 16 + ln15][qd * 8];
        #pragma unroll
        for (int c = 0; c < NT; ++c) {
            half8 b = *(const half8*)&Bs[c * 16 + ln15][qd * 8];
            acc[c] = __builtin_amdgcn_mfma_f32_16x16x32_f16(a, b, acc[c], 0, 0, 0);
        }
        __syncthreads();
    }

    // ---- epilogue ----
    int baseRow = bm + wv * 16 + qd * 4;
    #pragma unroll
    for (int c = 0; c < NT; ++c) {
        int col = c * 16 + ln15;
        if constexpr (std::is_same<OT, _Float16>::value) {
            #pragma unroll
            for (int r = 0; r < 4; ++r) {
                int row = baseRow + r;
                if (row < M) C[(size_t)row * N + col] = (_Float16)acc[c][r];
            }
        } else {
            float bv = (col < N && bias) ? bias[col] : 0.f;
            #pragma unroll
            for (int r = 0; r < 4; ++r) {
                int row = baseRow + r;
                if (row < M && col < N)
                    ((float*)C)[(size_t)row * N + col] = acc[c][r] + bv;
            }
        }
    }
}

// ---------------------------- aggregation ----------------------------------
// One wave per node; lane covers 2 cols (one packed __half2 = 4 B).
// fp32 accumulate; writes fp16 (feeds next GEMM's A staging directly).

static __device__ __forceinline__ float2 h2f2(unsigned int raw) {
    __half2 h = *(__half2*)&raw;
    return __half22float2(h);
}

__global__ __launch_bounds__(256) void gcn_agg(const unsigned int* __restrict__ h,
                                               const int* __restrict__ rowptr,
                                               const int* __restrict__ colArr,
                                               const float* __restrict__ dinv,
                                               const float* __restrict__ bias,
                                               unsigned int* __restrict__ out,
                                               int n, int do_relu) {
    int node = blockIdx.x * 4 + (threadIdx.x >> 6);
    if (node >= n) return;
    int lane = threadIdx.x & 63;

    float di = dinv[node];
    float2 v = h2f2(h[(size_t)node * 64 + lane]);
    float s  = di * di;
    float accx = v.x * s;
    float accy = v.y * s;

    int e0 = rowptr[node];
    int e1 = rowptr[node + 1];
    int e  = e0;

    for (; e + 4 <= e1; e += 4) {
        int j0 = colArr[e + 0];
        int j1 = colArr[e + 1];
        int j2 = colArr[e + 2];
        int j3 = colArr[e + 3];
        float w0 = dinv[j0];
        float w1 = dinv[j1];
        float w2 = dinv[j2];
        float w3 = dinv[j3];
        unsigned int r0 = h[(size_t)j0 * 64 + lane];
        unsigned int r1 = h[(size_t)j1 * 64 + lane];
        unsigned int r2 = h[(size_t)j2 * 64 + lane];
        unsigned int r3 = h[(size_t)j3 * 64 + lane];
        w0 *= di; w1 *= di; w2 *= di; w3 *= di;
        float2 u0 = h2f2(r0);
        float2 u1 = h2f2(r1);
        float2 u2 = h2f2(r2);
        float2 u3 = h2f2(r3);
        accx += u0.x * w0;
        accy += u0.y * w0;
        accx += u1.x * w1;
        accy += u1.y * w1;
        accx += u2.x * w2;
        accy += u2.y * w2;
        accx += u3.x * w3;
        accy += u3.y * w3;
    }
    for (; e < e1; ++e) {
        int j = colArr[e];
        float w = di * dinv[j];
        float2 u = h2f2(h[(size_t)j * 64 + lane]);
        accx += u.x * w;
        accy += u.y * w;
    }

    float2 b = ((const float2*)bias)[lane];
    float ox = accx + b.x;
    float oy = accy + b.y;
    if (do_relu) {
        ox = fmaxf(ox, 0.f);
        oy = fmaxf(oy, 0.f);
    }
    __half2 p = __floats2half2_rn(ox, oy);
    out[(size_t)node * 64 + lane] = *(unsigned int*)&p;
}

// ------------------------------- launch ------------------------------------

extern "C" void kernel_launch(void* const* d_in, const int* in_sizes, int n_in,
                              void* d_out, int out_size, void* d_ws, size_t ws_size,
                              hipStream_t stream) {
    const float* x  = (const float*)d_in[0];
    const int* eidx = (const int*)d_in[1];
    const float* W1 = (const float*)d_in[2];
    const float* b1 = (const float*)d_in[3];
    const float* W2 = (const float*)d_in[4];
    const float* b2 = (const float*)d_in[5];
    const float* Wc = (const float*)d_in[6];
    const float* bc = (const float*)d_in[7];
    float* out = (float*)d_out;

    const int NF = 256, NH = 128, NC = 40;
    const int n = in_sizes[0] / NF;    // 100000
    const int E = in_sizes[1] / 2;     // 1600000
    const int m = 8 * n;
    const int* src = eidx;
    const int* dst = eidx + E;

    char* wsb = (char*)d_ws;
    size_t off = 0;
    auto alloc = [&](size_t bytes) {
        char* p = wsb + off;
        off = (off + bytes + 511) & ~(size_t)511;
        return p;
    };
    _Float16* hbuf = (_Float16*)alloc((size_t)n * NH * 2);  // 25.6 MB
    _Float16* abuf = (_Float16*)alloc((size_t)n * NH * 2);  // 25.6 MB
    _Float16* W1t  = (_Float16*)alloc((size_t)128 * 256 * 2);
    _Float16* W2t  = (_Float16*)alloc((size_t)128 * 128 * 2);
    _Float16* Wct  = (_Float16*)alloc((size_t)48 * 128 * 2);
    int* colArr    = (int*)alloc((size_t)E * 4);
    int* col8      = (int*)alloc((size_t)E * 4);
    int* deg8      = (int*)alloc((size_t)m * 4);
    int* rowptr8   = (int*)alloc((size_t)(m + 1) * 4);
    int* cursor8   = (int*)alloc((size_t)m * 4);
    int* deg       = (int*)alloc((size_t)n * 4);
    int* rowptr    = (int*)alloc((size_t)(n + 1) * 4);
    float* dinv    = (float*)alloc((size_t)n * 4);
    int* bsumA     = (int*)alloc(1024);
    int* bsumB     = (int*)alloc(1024);

    const int gE  = (E + 255) / 256;
    const int gN  = (n + 255) / 256;
    const int gM8 = (m + 255) / 256;
    const int nbA = (m + 4095) / 4096;
    const int nbB = (n + 1023) / 1024;

    hipMemsetAsync(deg8, 0, (size_t)m * 4, stream);
    k_deg8<<<gE, 256, 0, stream>>>(dst, deg8, n, E);
    k_degsum<<<gN, 256, 0, stream>>>(deg8, deg, dinv, n);
    k_scan1<16><<<nbA, 256, 0, stream>>>(deg8, bsumA, m);
    k_scan2<<<1, 256, 0, stream>>>(bsumA, nbA);
    k_scan3<16><<<nbA, 256, 0, stream>>>(deg8, bsumA, rowptr8, m);
    k_scan1<4><<<nbB, 256, 0, stream>>>(deg, bsumB, n);
    k_scan2<<<1, 256, 0, stream>>>(bsumB, nbB);
    k_scan3<4><<<nbB, 256, 0, stream>>>(deg, bsumB, rowptr, n);
    k_cursor8<<<gM8, 256, 0, stream>>>(rowptr8, cursor8, rowptr8 + m, rowptr + n, m, E);
    k_scatter8<<<gE, 256, 0, stream>>>(src, dst, cursor8, col8, n, E);
    k_compact<<<gN, 256, 0, stream>>>(rowptr8, col8, rowptr, colArr, n);

    // weight transpose+cast (tiny)
    k_wcast<<<(128 * 256 + 255) / 256, 256, 0, stream>>>(W1, W1t, 128, 256, 8, 128 * 256);
    k_wcast<<<(128 * 128 + 255) / 256, 256, 0, stream>>>(W2, W2t, 128, 128, 7, 128 * 128);
    k_wcast<<<(48 * 128 + 255) / 256, 256, 0, stream>>>(Wc, Wct, 40, 128, 7, 48 * 128);

    const int gMt = (n + 63) / 64;   // 1563
    gemm_mfma<256, 128, float, _Float16><<<gMt, 256, 0, stream>>>(x, W1t, nullptr, hbuf, n, NH);
    gcn_agg<<<(n + 3) / 4, 256, 0, stream>>>((const unsigned int*)hbuf, rowptr, colArr, dinv, b1,
                                             (unsigned int*)abuf, n, 1);
    gemm_mfma<128, 128, _Float16, _Float16><<<gMt, 256, 0, stream>>>(abuf, W2t, nullptr, hbuf, n, NH);
    gcn_agg<<<(n + 3) / 4, 256, 0, stream>>>((const unsigned int*)hbuf, rowptr, colArr, dinv, b2,
                                             (unsigned int*)abuf, n, 1);
    gemm_mfma<128, 48, _Float16, float><<<gMt, 256, 0, stream>>>(abuf, Wct, bc, out, n, NC);
}

// Round 6
// 534.163 us; speedup vs baseline: 1.5644x; 1.0280x over previous
//
#include <hip/hip_runtime.h>
#include <hip/hip_bf16.h>
#include <hip/hip_fp16.h>
#include <type_traits>

// ---------------------------------------------------------------------------
// GCN: out = relu(Agg(x@W1)+b1) -> relu(Agg(.@W2)+b2) -> .@Wc+bc
// Agg(h)[i] = dinv[i]^2*h[i] + sum_{e: dst=i} dinv[i]*dinv[src]*h[src]
// R1: agg edge-loop unrolled x4 (latency fix).
// R2: XCD-sharded counting sort (k_scatter 130us/105MB-write -> ~15us).
// R3: h intermediates 2-byte: gather row 512B->256B (agg 123->~77us).
// R4: MFMA fp16 GEMMs (GEMM1 126->out of top5); fp16 h/a buffers.
// R5: agg VALUBusy 42% = per-edge broadcast loads (colArr, dinv) + per-lane
//     64-bit addr math. -> edge records int2{col,w} precomputed in compact;
//     lane-cooperative coalesced edge fetch + readlane broadcast: gather
//     becomes saddr-form global_load (SGPR base, lane offset), w in SGPR.
// ---------------------------------------------------------------------------

typedef _Float16 half8 __attribute__((ext_vector_type(8)));
typedef _Float16 half4v __attribute__((ext_vector_type(4)));
typedef float floatx4 __attribute__((ext_vector_type(4)));

// ------------------------- preprocessing kernels ---------------------------

__global__ __launch_bounds__(256) void k_deg8(const int* __restrict__ dst,
                                              int* __restrict__ deg8,
                                              int n, int E) {
    int i = blockIdx.x * 256 + threadIdx.x;
    if (i < E) {
        int s = (i >> 8) & 7;
        atomicAdd(&deg8[s * n + dst[i]], 1);
    }
}

__global__ __launch_bounds__(256) void k_degsum(const int* __restrict__ deg8,
                                                int* __restrict__ deg,
                                                float* __restrict__ dinv, int n) {
    int i = blockIdx.x * 256 + threadIdx.x;
    if (i < n) {
        int d = 0;
        #pragma unroll
        for (int s = 0; s < 8; ++s) d += deg8[s * n + i];
        deg[i] = d;
        dinv[i] = rsqrtf((float)(d + 1));
    }
}

__device__ inline int block_incl_scan_256(int t, int* tmp) {
    int tid = threadIdx.x;
    tmp[tid] = t;
    __syncthreads();
    #pragma unroll
    for (int off = 1; off < 256; off <<= 1) {
        int v = (tid >= off) ? tmp[tid - off] : 0;
        __syncthreads();
        tmp[tid] += v;
        __syncthreads();
    }
    return tmp[tid];
}

template <int ITEMS>
__global__ __launch_bounds__(256) void k_scan1(const int* __restrict__ v,
                                               int* __restrict__ bsum, int n) {
    __shared__ int tmp[256];
    int base = blockIdx.x * (256 * ITEMS) + threadIdx.x * ITEMS;
    int t = 0;
    #pragma unroll
    for (int l = 0; l < ITEMS; ++l) {
        int i = base + l;
        t += (i < n) ? v[i] : 0;
    }
    block_incl_scan_256(t, tmp);
    if (threadIdx.x == 0) bsum[blockIdx.x] = tmp[255];
}

__global__ __launch_bounds__(256) void k_scan2(int* __restrict__ bsum, int nb) {
    __shared__ int tmp[256];
    int tid = threadIdx.x;
    int v = (tid < nb) ? bsum[tid] : 0;
    block_incl_scan_256(v, tmp);
    if (tid < nb) bsum[tid] = tid ? tmp[tid - 1] : 0;
}

template <int ITEMS>
__global__ __launch_bounds__(256) void k_scan3(const int* __restrict__ vin,
                                               const int* __restrict__ bsum,
                                               int* __restrict__ rp, int n) {
    __shared__ int tmp[256];
    int base = blockIdx.x * (256 * ITEMS) + threadIdx.x * ITEMS;
    int v[ITEMS];
    int t = 0;
    #pragma unroll
    for (int l = 0; l < ITEMS; ++l) {
        int i = base + l;
        v[l] = (i < n) ? vin[i] : 0;
        t += v[l];
    }
    block_incl_scan_256(t, tmp);
    int run = bsum[blockIdx.x] + (threadIdx.x ? tmp[threadIdx.x - 1] : 0);
    #pragma unroll
    for (int l = 0; l < ITEMS; ++l) {
        int i = base + l;
        if (i < n) rp[i] = run;
        run += v[l];
    }
}

__global__ __launch_bounds__(256) void k_cursor8(const int* __restrict__ rowptr8,
                                                 int* __restrict__ cursor8,
                                                 int* __restrict__ rowptr8_end,
                                                 int* __restrict__ rowptr_end,
                                                 int m, int E) {
    int i = blockIdx.x * 256 + threadIdx.x;
    if (i < m) cursor8[i] = rowptr8[i];
    if (i == 0) { rowptr8_end[0] = E; rowptr_end[0] = E; }
}

__global__ __launch_bounds__(256) void k_scatter8(const int* __restrict__ src,
                                                  const int* __restrict__ dst,
                                                  int* __restrict__ cursor8,
                                                  int* __restrict__ col8,
                                                  int n, int E) {
    int i = blockIdx.x * 256 + threadIdx.x;
    if (i < E) {
        int s = (i >> 8) & 7;
        int d = dst[i];
        int p = atomicAdd(&cursor8[s * n + d], 1);
        col8[p] = src[i];
    }
}

// merge shard segments into node-major edge records {col, w=dinv_i*dinv_col}
__global__ __launch_bounds__(256) void k_compact(const int* __restrict__ rowptr8,
                                                 const int* __restrict__ col8,
                                                 const int* __restrict__ rowptr,
                                                 const float* __restrict__ dinv,
                                                 int2* __restrict__ edges, int n) {
    int i = blockIdx.x * 256 + threadIdx.x;
    if (i >= n) return;
    int p = rowptr[i];
    float di = dinv[i];
    #pragma unroll
    for (int s = 0; s < 8; ++s) {
        int a = rowptr8[s * n + i];
        int b = rowptr8[s * n + i + 1];
        for (int e = a; e < b; ++e) {
            int c = col8[e];
            float w = di * dinv[c];
            edges[p++] = make_int2(c, __float_as_int(w));
        }
    }
}

// W[K][N] fp32 -> Wt[NP][K] fp16, zero-padded for c in [N, NP). K pow2.
__global__ __launch_bounds__(256) void k_wcast(const float* __restrict__ W,
                                               _Float16* __restrict__ Wt,
                                               int N, int K, int kbits, int total) {
    int i = blockIdx.x * 256 + threadIdx.x;
    if (i < total) {
        int c = i >> kbits;
        int k = i & (K - 1);
        Wt[i] = (c < N) ? (_Float16)W[(size_t)k * N + c] : (_Float16)0.f;
    }
}

// ---------------------------- MFMA GEMM ------------------------------------
// C[M,N] = A[M,K] @ W[K,N] via v_mfma_f32_16x16x32_f16.
// Wt pre-transposed [BN][K] fp16. BM=64, BK=32, 4 waves.
// LDS stride 40 halfs: b128 frag reads <=2-way bank aliasing.

template <int K, int BN, typename AT, typename OT>
__global__ __launch_bounds__(256) void gemm_mfma(const AT* __restrict__ A,
                                                 const _Float16* __restrict__ Wt,
                                                 const float* __restrict__ bias,
                                                 OT* __restrict__ C,
                                                 int M, int N) {
    constexpr int NT = BN / 16;
    __shared__ __align__(16) _Float16 As[64][40];
    __shared__ __align__(16) _Float16 Bs[BN][40];

    const int tid  = threadIdx.x;
    const int bm   = blockIdx.x * 64;
    const int lane = tid & 63;
    const int wv   = tid >> 6;
    const int qd   = lane >> 4;
    const int ln15 = lane & 15;

    floatx4 acc[NT];
    #pragma unroll
    for (int c = 0; c < NT; ++c) acc[c] = (floatx4){0.f, 0.f, 0.f, 0.f};

    for (int k0 = 0; k0 < K; k0 += 32) {
        if constexpr (std::is_same<AT, float>::value) {
            #pragma unroll
            for (int l = 0; l < 2; ++l) {
                int f4  = tid + l * 256;
                int row = f4 >> 3;
                int kk  = (f4 & 7) << 2;
                float4 v = make_float4(0.f, 0.f, 0.f, 0.f);
                if (bm + row < M)
                    v = *(const float4*)(A + (size_t)(bm + row) * K + k0 + kk);
                half4v h;
                h[0] = (_Float16)v.x; h[1] = (_Float16)v.y;
                h[2] = (_Float16)v.z; h[3] = (_Float16)v.w;
                *(half4v*)&As[row][kk] = h;
            }
        } else {
            int row = tid >> 2;
            int kk  = (tid & 3) << 3;
            uint4 v = make_uint4(0u, 0u, 0u, 0u);
            if (bm + row < M)
                v = *(const uint4*)((const _Float16*)A + (size_t)(bm + row) * K + k0 + kk);
            *(uint4*)&As[row][kk] = v;
        }
        #pragma unroll
        for (int l = 0; l < (BN * 4 + 255) / 256; ++l) {
            int idx = tid + l * 256;
            if (idx < BN * 4) {
                int col = idx >> 2;
                int kk  = (idx & 3) << 3;
                *(uint4*)&Bs[col][kk] =
                    *(const uint4*)(Wt + (size_t)col * K + k0 + kk);
            }
        }
        __syncthreads();

        half8 a = *(const half8*)&As[wv * 16 + ln15][qd * 8];
        #pragma unroll
        for (int c = 0; c < NT; ++c) {
            half8 b = *(const half8*)&Bs[c * 16 + ln15][qd * 8];
            acc[c] = __builtin_amdgcn_mfma_f32_16x16x32_f16(a, b, acc[c], 0, 0, 0);
        }
        __syncthreads();
    }

    int baseRow = bm + wv * 16 + qd * 4;
    #pragma unroll
    for (int c = 0; c < NT; ++c) {
        int col = c * 16 + ln15;
        if constexpr (std::is_same<OT, _Float16>::value) {
            #pragma unroll
            for (int r = 0; r < 4; ++r) {
                int row = baseRow + r;
                if (row < M) C[(size_t)row * N + col] = (_Float16)acc[c][r];
            }
        } else {
            float bv = (col < N && bias) ? bias[col] : 0.f;
            #pragma unroll
            for (int r = 0; r < 4; ++r) {
                int row = baseRow + r;
                if (row < M && col < N)
                    ((float*)C)[(size_t)row * N + col] = acc[c][r] + bv;
            }
        }
    }
}

// ---------------------------- aggregation ----------------------------------
// One wave per node; lane covers 2 cols (packed __half2). Lanes 0..cnt-1
// cooperatively load the node's edge records (one coalesced int2 load);
// wave iterates edges with readlane-broadcast col/w -> SGPR, so the row
// gather is saddr-form (scalar base + lane*4) and w is an SGPR fma operand.

static __device__ __forceinline__ float2 h2f2(unsigned int raw) {
    __half2 h = *(__half2*)&raw;
    return __half22float2(h);
}

__global__ __launch_bounds__(256) void gcn_agg(const unsigned int* __restrict__ h,
                                               const int* __restrict__ rowptr,
                                               const int2* __restrict__ edges,
                                               const float* __restrict__ dinv,
                                               const float* __restrict__ bias,
                                               unsigned int* __restrict__ out,
                                               int n, int do_relu) {
    int node = blockIdx.x * 4 + (threadIdx.x >> 6);
    if (node >= n) return;
    int lane = threadIdx.x & 63;

    float di = dinv[node];
    float2 v = h2f2(h[(size_t)node * 64 + lane]);
    float s  = di * di;
    float accx = v.x * s;
    float accy = v.y * s;

    int e0 = rowptr[node];
    int e1 = rowptr[node + 1];

    for (int ce = e0; ce < e1; ce += 64) {
        int cnt = e1 - ce;
        cnt = (cnt < 64) ? cnt : 64;
        int colv = 0, wval = 0;
        if (lane < cnt) {
            int2 er = edges[ce + lane];
            colv = er.x;
            wval = er.y;
        }
        int d = 0;
        for (; d + 4 <= cnt; d += 4) {
            int c0 = __builtin_amdgcn_readlane(colv, d + 0);
            int c1 = __builtin_amdgcn_readlane(colv, d + 1);
            int c2 = __builtin_amdgcn_readlane(colv, d + 2);
            int c3 = __builtin_amdgcn_readlane(colv, d + 3);
            float w0 = __int_as_float(__builtin_amdgcn_readlane(wval, d + 0));
            float w1 = __int_as_float(__builtin_amdgcn_readlane(wval, d + 1));
            float w2 = __int_as_float(__builtin_amdgcn_readlane(wval, d + 2));
            float w3 = __int_as_float(__builtin_amdgcn_readlane(wval, d + 3));
            unsigned r0 = h[(size_t)(unsigned)c0 * 64 + lane];
            unsigned r1 = h[(size_t)(unsigned)c1 * 64 + lane];
            unsigned r2 = h[(size_t)(unsigned)c2 * 64 + lane];
            unsigned r3 = h[(size_t)(unsigned)c3 * 64 + lane];
            float2 u0 = h2f2(r0);
            float2 u1 = h2f2(r1);
            float2 u2 = h2f2(r2);
            float2 u3 = h2f2(r3);
            accx += u0.x * w0;
            accy += u0.y * w0;
            accx += u1.x * w1;
            accy += u1.y * w1;
            accx += u2.x * w2;
            accy += u2.y * w2;
            accx += u3.x * w3;
            accy += u3.y * w3;
        }
        for (; d < cnt; ++d) {
            int c = __builtin_amdgcn_readlane(colv, d);
            float w = __int_as_float(__builtin_amdgcn_readlane(wval, d));
            float2 u = h2f2(h[(size_t)(unsigned)c * 64 + lane]);
            accx += u.x * w;
            accy += u.y * w;
        }
    }

    float2 b = ((const float2*)bias)[lane];
    float ox = accx + b.x;
    float oy = accy + b.y;
    if (do_relu) {
        ox = fmaxf(ox, 0.f);
        oy = fmaxf(oy, 0.f);
    }
    __half2 p = __floats2half2_rn(ox, oy);
    out[(size_t)node * 64 + lane] = *(unsigned int*)&p;
}

// ------------------------------- launch ------------------------------------

extern "C" void kernel_launch(void* const* d_in, const int* in_sizes, int n_in,
                              void* d_out, int out_size, void* d_ws, size_t ws_size,
                              hipStream_t stream) {
    const float* x  = (const float*)d_in[0];
    const int* eidx = (const int*)d_in[1];
    const float* W1 = (const float*)d_in[2];
    const float* b1 = (const float*)d_in[3];
    const float* W2 = (const float*)d_in[4];
    const float* b2 = (const float*)d_in[5];
    const float* Wc = (const float*)d_in[6];
    const float* bc = (const float*)d_in[7];
    float* out = (float*)d_out;

    const int NF = 256, NH = 128, NC = 40;
    const int n = in_sizes[0] / NF;    // 100000
    const int E = in_sizes[1] / 2;     // 1600000
    const int m = 8 * n;
    const int* src = eidx;
    const int* dst = eidx + E;

    char* wsb = (char*)d_ws;
    size_t off = 0;
    auto alloc = [&](size_t bytes) {
        char* p = wsb + off;
        off = (off + bytes + 511) & ~(size_t)511;
        return p;
    };
    _Float16* hbuf = (_Float16*)alloc((size_t)n * NH * 2);  // 25.6 MB
    _Float16* abuf = (_Float16*)alloc((size_t)n * NH * 2);  // 25.6 MB
    _Float16* W1t  = (_Float16*)alloc((size_t)128 * 256 * 2);
    _Float16* W2t  = (_Float16*)alloc((size_t)128 * 128 * 2);
    _Float16* Wct  = (_Float16*)alloc((size_t)48 * 128 * 2);
    int2* edges    = (int2*)alloc((size_t)E * 8);           // 12.8 MB
    int* col8      = (int*)alloc((size_t)E * 4);
    int* deg8      = (int*)alloc((size_t)m * 4);
    int* rowptr8   = (int*)alloc((size_t)(m + 1) * 4);
    int* cursor8   = (int*)alloc((size_t)m * 4);
    int* deg       = (int*)alloc((size_t)n * 4);
    int* rowptr    = (int*)alloc((size_t)(n + 1) * 4);
    float* dinv    = (float*)alloc((size_t)n * 4);
    int* bsumA     = (int*)alloc(1024);
    int* bsumB     = (int*)alloc(1024);

    const int gE  = (E + 255) / 256;
    const int gN  = (n + 255) / 256;
    const int gM8 = (m + 255) / 256;
    const int nbA = (m + 4095) / 4096;
    const int nbB = (n + 1023) / 1024;

    hipMemsetAsync(deg8, 0, (size_t)m * 4, stream);
    k_deg8<<<gE, 256, 0, stream>>>(dst, deg8, n, E);
    k_degsum<<<gN, 256, 0, stream>>>(deg8, deg, dinv, n);
    k_scan1<16><<<nbA, 256, 0, stream>>>(deg8, bsumA, m);
    k_scan2<<<1, 256, 0, stream>>>(bsumA, nbA);
    k_scan3<16><<<nbA, 256, 0, stream>>>(deg8, bsumA, rowptr8, m);
    k_scan1<4><<<nbB, 256, 0, stream>>>(deg, bsumB, n);
    k_scan2<<<1, 256, 0, stream>>>(bsumB, nbB);
    k_scan3<4><<<nbB, 256, 0, stream>>>(deg, bsumB, rowptr, n);
    k_cursor8<<<gM8, 256, 0, stream>>>(rowptr8, cursor8, rowptr8 + m, rowptr + n, m, E);
    k_scatter8<<<gE, 256, 0, stream>>>(src, dst, cursor8, col8, n, E);
    k_compact<<<gN, 256, 0, stream>>>(rowptr8, col8, rowptr, dinv, edges, n);

    k_wcast<<<(128 * 256 + 255) / 256, 256, 0, stream>>>(W1, W1t, 128, 256, 8, 128 * 256);
    k_wcast<<<(128 * 128 + 255) / 256, 256, 0, stream>>>(W2, W2t, 128, 128, 7, 128 * 128);
    k_wcast<<<(48 * 128 + 255) / 256, 256, 0, stream>>>(Wc, Wct, 40, 128, 7, 48 * 128);

    const int gMt = (n + 63) / 64;   // 1563
    gemm_mfma<256, 128, float, _Float16><<<gMt, 256, 0, stream>>>(x, W1t, nullptr, hbuf, n, NH);
    gcn_agg<<<(n + 3) / 4, 256, 0, stream>>>((const unsigned int*)hbuf, rowptr, edges, dinv, b1,
                                             (unsigned int*)abuf, n, 1);
    gemm_mfma<128, 128, _Float16, _Float16><<<gMt, 256, 0, stream>>>(abuf, W2t, nullptr, hbuf, n, NH);
    gcn_agg<<<(n + 3) / 4, 256, 0, stream>>>((const unsigned int*)hbuf, rowptr, edges, dinv, b2,
                                             (unsigned int*)abuf, n, 1);
    gemm_mfma<128, 48, _Float16, float><<<gMt, 256, 0, stream>>>(abuf, Wct, bc, out, n, NC);
}

// Round 7
// 421.829 us; speedup vs baseline: 1.9811x; 1.2663x over previous
//
#include <hip/hip_runtime.h>
#include <hip/hip_bf16.h>
#include <hip/hip_fp16.h>
#include <type_traits>

// ---------------------------------------------------------------------------
// GCN: out = relu(Agg(x@W1)+b1) -> relu(Agg(.@W2)+b2) -> .@Wc+bc
// Agg(h)[i] = dinv[i]^2*h[i] + sum_{e: dst=i} dinv[i]*dinv[src]*h[src]
// R1: agg edge-loop unrolled x4 (latency fix).
// R2: XCD-sharded counting sort.
// R3: h intermediates 2-byte (gather row 512B->256B).
// R4: MFMA fp16 GEMMs; fp16 h/a buffers.
// R5: agg lane-coop edge fetch + readlane broadcast (VALU 42%->).
// R6: atomic CSR build was the bottleneck (k_scatter8 68us, WRITE 60MB =
//     9.4x line amp; k_deg8 similar hidden cost). -> 2-level MSD bucket
//     sort, zero global atomics: histA(dst>>8, LDS) -> scan -> scatterA
//     (bucket-grouped 128B runs) -> sortB (per-bucket LDS counting sort by
//     dst&255; emits srcS coalesced + rowptr/deg/dinv via LDS bsearch).
//     agg reads srcS (4B/edge) and gathers dinv[src] per lane.
// ---------------------------------------------------------------------------

typedef _Float16 half8 __attribute__((ext_vector_type(8)));
typedef _Float16 half4v __attribute__((ext_vector_type(4)));
typedef float floatx4 __attribute__((ext_vector_type(4)));

#define EPB 8192   // edges per block in histA/scatterA

// ------------------------- scan helpers (unchanged) ------------------------

__device__ inline int block_incl_scan_256(int t, int* tmp) {
    int tid = threadIdx.x;
    tmp[tid] = t;
    __syncthreads();
    #pragma unroll
    for (int off = 1; off < 256; off <<= 1) {
        int v = (tid >= off) ? tmp[tid - off] : 0;
        __syncthreads();
        tmp[tid] += v;
        __syncthreads();
    }
    return tmp[tid];
}

template <int ITEMS>
__global__ __launch_bounds__(256) void k_scan1(const int* __restrict__ v,
                                               int* __restrict__ bsum, int n) {
    __shared__ int tmp[256];
    int base = blockIdx.x * (256 * ITEMS) + threadIdx.x * ITEMS;
    int t = 0;
    #pragma unroll
    for (int l = 0; l < ITEMS; ++l) {
        int i = base + l;
        t += (i < n) ? v[i] : 0;
    }
    block_incl_scan_256(t, tmp);
    if (threadIdx.x == 0) bsum[blockIdx.x] = tmp[255];
}

__global__ __launch_bounds__(256) void k_scan2(int* __restrict__ bsum, int nb) {
    __shared__ int tmp[256];
    int tid = threadIdx.x;
    int v = (tid < nb) ? bsum[tid] : 0;
    block_incl_scan_256(v, tmp);
    if (tid < nb) bsum[tid] = tid ? tmp[tid - 1] : 0;
}

template <int ITEMS>
__global__ __launch_bounds__(256) void k_scan3(const int* __restrict__ vin,
                                               const int* __restrict__ bsum,
                                               int* __restrict__ rp, int n) {
    __shared__ int tmp[256];
    int base = blockIdx.x * (256 * ITEMS) + threadIdx.x * ITEMS;
    int v[ITEMS];
    int t = 0;
    #pragma unroll
    for (int l = 0; l < ITEMS; ++l) {
        int i = base + l;
        v[l] = (i < n) ? vin[i] : 0;
        t += v[l];
    }
    block_incl_scan_256(t, tmp);
    int run = bsum[blockIdx.x] + (threadIdx.x ? tmp[threadIdx.x - 1] : 0);
    #pragma unroll
    for (int l = 0; l < ITEMS; ++l) {
        int i = base + l;
        if (i < n) rp[i] = run;
        run += v[l];
    }
}

// ----------------------- bucket-sort CSR build -----------------------------

// per-block histogram of coarse bucket (dst>>8); histM[bucket*nblk + blk]
__global__ __launch_bounds__(256) void k_histA(const int* __restrict__ dst,
                                               int* __restrict__ histM,
                                               int E, int nblk) {
    __shared__ int h[512];
    int tid = threadIdx.x;
    for (int i = tid; i < 512; i += 256) h[i] = 0;
    __syncthreads();
    int base = blockIdx.x * EPB;
    #pragma unroll 4
    for (int l = 0; l < EPB / 256; ++l) {
        int i = base + l * 256 + tid;
        if (i < E) atomicAdd(&h[dst[i] >> 8], 1);
    }
    __syncthreads();
    for (int i = tid; i < 512; i += 256)
        histM[i * nblk + blockIdx.x] = h[i];
}

// scatter edges into bucket-grouped u64 array; each (block,bucket) run is
// contiguous -> ~128B coalesced runs, no global atomics.
__global__ __launch_bounds__(256) void k_scatterA(const int* __restrict__ src,
                                                  const int* __restrict__ dst,
                                                  const int* __restrict__ histS,
                                                  unsigned long long* __restrict__ eB,
                                                  int E, int nblk) {
    __shared__ int bse[512];
    __shared__ int cnt[512];
    int tid = threadIdx.x;
    for (int i = tid; i < 512; i += 256) {
        bse[i] = histS[i * nblk + blockIdx.x];
        cnt[i] = 0;
    }
    __syncthreads();
    int base = blockIdx.x * EPB;
    #pragma unroll 4
    for (int l = 0; l < EPB / 256; ++l) {
        int i = base + l * 256 + tid;
        if (i < E) {
            int d = dst[i];
            int s = src[i];
            int b = d >> 8;
            int r = atomicAdd(&cnt[b], 1);
            eB[bse[b] + r] = ((unsigned long long)(unsigned)d << 32) | (unsigned)s;
        }
    }
}

// one block per coarse bucket: LDS counting sort by dst&255 -> fully sorted;
// writes srcS coalesced; computes rowptr/deg/dinv for its 256 nodes via
// LDS binary search over the sorted dst values.
#define BCAP 4608   // bucket capacity: mean 4096, sigma~64 -> 8 sigma head
__global__ __launch_bounds__(256) void k_sortB(const unsigned long long* __restrict__ eB,
                                               const int* __restrict__ histS,
                                               int* __restrict__ srcS,
                                               int* __restrict__ rowptr,
                                               float* __restrict__ dinv,
                                               int n, int E, int nblk) {
    const int b   = blockIdx.x;
    const int tid = threadIdx.x;
    const int ni0 = b << 8;
    int s0 = histS[b * nblk];
    int s1 = (b < 511) ? histS[(b + 1) * nblk] : E;
    int cnt = s1 - s0;
    if (cnt > BCAP) cnt = BCAP;          // statistically unreachable
    if (cnt == 0 && ni0 > n) return;

    __shared__ int hist[256];
    __shared__ int tmp[256];
    __shared__ int baseA[256];
    __shared__ int cntA[256];
    __shared__ int dstL[BCAP];
    __shared__ unsigned srcL[BCAP];
    __shared__ int lbA[256];

    hist[tid] = 0;
    cntA[tid] = 0;
    __syncthreads();
    for (int i = s0 + tid; i < s0 + cnt; i += 256) {
        int d = (int)(eB[i] >> 32);
        atomicAdd(&hist[d & 255], 1);
    }
    __syncthreads();
    int own  = hist[tid];
    int incl = block_incl_scan_256(own, tmp);
    baseA[tid] = incl - own;
    __syncthreads();
    for (int i = s0 + tid; i < s0 + cnt; i += 256) {
        unsigned long long v = eB[i];
        int d = (int)(v >> 32);
        int dig = d & 255;
        int r = atomicAdd(&cntA[dig], 1);
        int pos = baseA[dig] + r;
        dstL[pos] = d;
        srcL[pos] = (unsigned)v;
    }
    __syncthreads();
    // coalesced src emit
    for (int j = tid; j < cnt; j += 256)
        srcS[s0 + j] = (int)srcL[j];
    // rowptr / dinv for nodes [ni0, ni0+256) (and rowptr[n] if it falls here)
    if (ni0 <= n) {
        int i = ni0 + tid;
        int lo = 0, hi = cnt;
        while (lo < hi) {
            int mid = (lo + hi) >> 1;
            if (dstL[mid] < i) lo = mid + 1; else hi = mid;
        }
        lbA[tid] = lo;
        __syncthreads();
        if (i <= n) {
            rowptr[i] = s0 + lo;
            if (i < n) {
                int ub = (tid < 255) ? lbA[tid + 1] : cnt;
                dinv[i] = rsqrtf((float)(ub - lo + 1));
            }
        }
    }
}

// W[K][N] fp32 -> Wt[NP][K] fp16, zero-padded for c in [N, NP). K pow2.
__global__ __launch_bounds__(256) void k_wcast(const float* __restrict__ W,
                                               _Float16* __restrict__ Wt,
                                               int N, int K, int kbits, int total) {
    int i = blockIdx.x * 256 + threadIdx.x;
    if (i < total) {
        int c = i >> kbits;
        int k = i & (K - 1);
        Wt[i] = (c < N) ? (_Float16)W[(size_t)k * N + c] : (_Float16)0.f;
    }
}

// ---------------------------- MFMA GEMM ------------------------------------
// C[M,N] = A[M,K] @ W[K,N] via v_mfma_f32_16x16x32_f16.
// Wt pre-transposed [BN][K] fp16. BM=64, BK=32, 4 waves.
// LDS stride 40 halfs: b128 frag reads <=2-way bank aliasing.

template <int K, int BN, typename AT, typename OT>
__global__ __launch_bounds__(256) void gemm_mfma(const AT* __restrict__ A,
                                                 const _Float16* __restrict__ Wt,
                                                 const float* __restrict__ bias,
                                                 OT* __restrict__ C,
                                                 int M, int N) {
    constexpr int NT = BN / 16;
    __shared__ __align__(16) _Float16 As[64][40];
    __shared__ __align__(16) _Float16 Bs[BN][40];

    const int tid  = threadIdx.x;
    const int bm   = blockIdx.x * 64;
    const int lane = tid & 63;
    const int wv   = tid >> 6;
    const int qd   = lane >> 4;
    const int ln15 = lane & 15;

    floatx4 acc[NT];
    #pragma unroll
    for (int c = 0; c < NT; ++c) acc[c] = (floatx4){0.f, 0.f, 0.f, 0.f};

    for (int k0 = 0; k0 < K; k0 += 32) {
        if constexpr (std::is_same<AT, float>::value) {
            #pragma unroll
            for (int l = 0; l < 2; ++l) {
                int f4  = tid + l * 256;
                int row = f4 >> 3;
                int kk  = (f4 & 7) << 2;
                float4 v = make_float4(0.f, 0.f, 0.f, 0.f);
                if (bm + row < M)
                    v = *(const float4*)(A + (size_t)(bm + row) * K + k0 + kk);
                half4v h;
                h[0] = (_Float16)v.x; h[1] = (_Float16)v.y;
                h[2] = (_Float16)v.z; h[3] = (_Float16)v.w;
                *(half4v*)&As[row][kk] = h;
            }
        } else {
            int row = tid >> 2;
            int kk  = (tid & 3) << 3;
            uint4 v = make_uint4(0u, 0u, 0u, 0u);
            if (bm + row < M)
                v = *(const uint4*)((const _Float16*)A + (size_t)(bm + row) * K + k0 + kk);
            *(uint4*)&As[row][kk] = v;
        }
        #pragma unroll
        for (int l = 0; l < (BN * 4 + 255) / 256; ++l) {
            int idx = tid + l * 256;
            if (idx < BN * 4) {
                int col = idx >> 2;
                int kk  = (idx & 3) << 3;
                *(uint4*)&Bs[col][kk] =
                    *(const uint4*)(Wt + (size_t)col * K + k0 + kk);
            }
        }
        __syncthreads();

        half8 a = *(const half8*)&As[wv * 16 + ln15][qd * 8];
        #pragma unroll
        for (int c = 0; c < NT; ++c) {
            half8 b = *(const half8*)&Bs[c * 16 + ln15][qd * 8];
            acc[c] = __builtin_amdgcn_mfma_f32_16x16x32_f16(a, b, acc[c], 0, 0, 0);
        }
        __syncthreads();
    }

    int baseRow = bm + wv * 16 + qd * 4;
    #pragma unroll
    for (int c = 0; c < NT; ++c) {
        int col = c * 16 + ln15;
        if constexpr (std::is_same<OT, _Float16>::value) {
            #pragma unroll
            for (int r = 0; r < 4; ++r) {
                int row = baseRow + r;
                if (row < M) C[(size_t)row * N + col] = (_Float16)acc[c][r];
            }
        } else {
            float bv = (col < N && bias) ? bias[col] : 0.f;
            #pragma unroll
            for (int r = 0; r < 4; ++r) {
                int row = baseRow + r;
                if (row < M && col < N)
                    ((float*)C)[(size_t)row * N + col] = acc[c][r] + bv;
            }
        }
    }
}

// ---------------------------- aggregation ----------------------------------
// One wave per node; lane covers 2 cols (packed __half2). Lanes 0..cnt-1
// cooperatively load 64 src indices (coalesced 4B), gather dinv[src]
// (L2-resident 400KB table), compute w = di*dinv_src per lane; wave then
// iterates edges with readlane-broadcast col/w -> SGPR saddr-form gathers.

static __device__ __forceinline__ float2 h2f2(unsigned int raw) {
    __half2 h = *(__half2*)&raw;
    return __half22float2(h);
}

__global__ __launch_bounds__(256) void gcn_agg(const unsigned int* __restrict__ h,
                                               const int* __restrict__ rowptr,
                                               const int* __restrict__ srcS,
                                               const float* __restrict__ dinv,
                                               const float* __restrict__ bias,
                                               unsigned int* __restrict__ out,
                                               int n, int do_relu) {
    int node = blockIdx.x * 4 + (threadIdx.x >> 6);
    if (node >= n) return;
    int lane = threadIdx.x & 63;

    float di = dinv[node];
    float2 v = h2f2(h[(size_t)node * 64 + lane]);
    float s  = di * di;
    float accx = v.x * s;
    float accy = v.y * s;

    int e0 = rowptr[node];
    int e1 = rowptr[node + 1];

    for (int ce = e0; ce < e1; ce += 64) {
        int cnt = e1 - ce;
        cnt = (cnt < 64) ? cnt : 64;
        int colv = 0, wval = 0;
        if (lane < cnt) {
            int c = srcS[ce + lane];
            colv = c;
            wval = __float_as_int(di * dinv[c]);
        }
        int d = 0;
        for (; d + 4 <= cnt; d += 4) {
            int c0 = __builtin_amdgcn_readlane(colv, d + 0);
            int c1 = __builtin_amdgcn_readlane(colv, d + 1);
            int c2 = __builtin_amdgcn_readlane(colv, d + 2);
            int c3 = __builtin_amdgcn_readlane(colv, d + 3);
            float w0 = __int_as_float(__builtin_amdgcn_readlane(wval, d + 0));
            float w1 = __int_as_float(__builtin_amdgcn_readlane(wval, d + 1));
            float w2 = __int_as_float(__builtin_amdgcn_readlane(wval, d + 2));
            float w3 = __int_as_float(__builtin_amdgcn_readlane(wval, d + 3));
            unsigned r0 = h[(size_t)(unsigned)c0 * 64 + lane];
            unsigned r1 = h[(size_t)(unsigned)c1 * 64 + lane];
            unsigned r2 = h[(size_t)(unsigned)c2 * 64 + lane];
            unsigned r3 = h[(size_t)(unsigned)c3 * 64 + lane];
            float2 u0 = h2f2(r0);
            float2 u1 = h2f2(r1);
            float2 u2 = h2f2(r2);
            float2 u3 = h2f2(r3);
            accx += u0.x * w0;
            accy += u0.y * w0;
            accx += u1.x * w1;
            accy += u1.y * w1;
            accx += u2.x * w2;
            accy += u2.y * w2;
            accx += u3.x * w3;
            accy += u3.y * w3;
        }
        for (; d < cnt; ++d) {
            int c = __builtin_amdgcn_readlane(colv, d);
            float w = __int_as_float(__builtin_amdgcn_readlane(wval, d));
            float2 u = h2f2(h[(size_t)(unsigned)c * 64 + lane]);
            accx += u.x * w;
            accy += u.y * w;
        }
    }

    float2 b = ((const float2*)bias)[lane];
    float ox = accx + b.x;
    float oy = accy + b.y;
    if (do_relu) {
        ox = fmaxf(ox, 0.f);
        oy = fmaxf(oy, 0.f);
    }
    __half2 p = __floats2half2_rn(ox, oy);
    out[(size_t)node * 64 + lane] = *(unsigned int*)&p;
}

// ------------------------------- launch ------------------------------------

extern "C" void kernel_launch(void* const* d_in, const int* in_sizes, int n_in,
                              void* d_out, int out_size, void* d_ws, size_t ws_size,
                              hipStream_t stream) {
    const float* x  = (const float*)d_in[0];
    const int* eidx = (const int*)d_in[1];
    const float* W1 = (const float*)d_in[2];
    const float* b1 = (const float*)d_in[3];
    const float* W2 = (const float*)d_in[4];
    const float* b2 = (const float*)d_in[5];
    const float* Wc = (const float*)d_in[6];
    const float* bc = (const float*)d_in[7];
    float* out = (float*)d_out;

    const int NF = 256, NH = 128, NC = 40;
    const int n = in_sizes[0] / NF;    // 100000
    const int E = in_sizes[1] / 2;     // 1600000
    const int* src = eidx;
    const int* dst = eidx + E;

    const int nblk = (E + EPB - 1) / EPB;          // 196
    const int hm   = 512 * nblk;                   // 100352
    const int nbA  = (hm + 4095) / 4096;           // 25

    char* wsb = (char*)d_ws;
    size_t off = 0;
    auto alloc = [&](size_t bytes) {
        char* p = wsb + off;
        off = (off + bytes + 511) & ~(size_t)511;
        return p;
    };
    _Float16* hbuf = (_Float16*)alloc((size_t)n * NH * 2);  // 25.6 MB
    _Float16* abuf = (_Float16*)alloc((size_t)n * NH * 2);  // 25.6 MB
    _Float16* W1t  = (_Float16*)alloc((size_t)128 * 256 * 2);
    _Float16* W2t  = (_Float16*)alloc((size_t)128 * 128 * 2);
    _Float16* Wct  = (_Float16*)alloc((size_t)48 * 128 * 2);
    unsigned long long* eB = (unsigned long long*)alloc((size_t)E * 8);  // 12.8 MB
    int* srcS      = (int*)alloc((size_t)E * 4);            // 6.4 MB
    int* histM     = (int*)alloc((size_t)hm * 4);
    int* histS     = (int*)alloc((size_t)hm * 4);
    int* rowptr    = (int*)alloc((size_t)(n + 1) * 4);
    float* dinv    = (float*)alloc((size_t)n * 4);
    int* bsumA     = (int*)alloc(1024);

    // ---- CSR build: 2-level bucket sort, no global atomics ----
    k_histA<<<nblk, 256, 0, stream>>>(dst, histM, E, nblk);
    k_scan1<16><<<nbA, 256, 0, stream>>>(histM, bsumA, hm);
    k_scan2<<<1, 256, 0, stream>>>(bsumA, nbA);
    k_scan3<16><<<nbA, 256, 0, stream>>>(histM, bsumA, histS, hm);
    k_scatterA<<<nblk, 256, 0, stream>>>(src, dst, histS, eB, E, nblk);
    k_sortB<<<512, 256, 0, stream>>>(eB, histS, srcS, rowptr, dinv, n, E, nblk);

    // ---- weights ----
    k_wcast<<<(128 * 256 + 255) / 256, 256, 0, stream>>>(W1, W1t, 128, 256, 8, 128 * 256);
    k_wcast<<<(128 * 128 + 255) / 256, 256, 0, stream>>>(W2, W2t, 128, 128, 7, 128 * 128);
    k_wcast<<<(48 * 128 + 255) / 256, 256, 0, stream>>>(Wc, Wct, 40, 128, 7, 48 * 128);

    // ---- layers ----
    const int gMt = (n + 63) / 64;   // 1563
    gemm_mfma<256, 128, float, _Float16><<<gMt, 256, 0, stream>>>(x, W1t, nullptr, hbuf, n, NH);
    gcn_agg<<<(n + 3) / 4, 256, 0, stream>>>((const unsigned int*)hbuf, rowptr, srcS, dinv, b1,
                                             (unsigned int*)abuf, n, 1);
    gemm_mfma<128, 128, _Float16, _Float16><<<gMt, 256, 0, stream>>>(abuf, W2t, nullptr, hbuf, n, NH);
    gcn_agg<<<(n + 3) / 4, 256, 0, stream>>>((const unsigned int*)hbuf, rowptr, srcS, dinv, b2,
                                             (unsigned int*)abuf, n, 1);
    gemm_mfma<128, 48, _Float16, float><<<gMt, 256, 0, stream>>>(abuf, Wct, bc, out, n, NC);
}